// Round 9
// baseline (645.048 us; speedup 1.0000x reference)
//
#include <hip/hip_runtime.h>
#include <hip/hip_bf16.h>

#define N_NODES 100000
#define N_EDGES 1600000
#define N_GRAPHS 2048
#define F0 128
#define F1 256
#define NCLS 64

// bucketed CSR build
#define BSHIFT 9
#define BNODES 512
#define NB 196
#define EPB 4096
#define NCHUNK 391
#define FLATN (NB * NCHUNK)

typedef unsigned int uint32;
typedef unsigned short u16;
typedef u16 u16x8 __attribute__((ext_vector_type(8)));
typedef __bf16 bf16x8 __attribute__((ext_vector_type(8)));
typedef float f32x4 __attribute__((ext_vector_type(4)));

__device__ __forceinline__ float b16f(u16 v) { return __builtin_bit_cast(float, (uint32)v << 16); }
__device__ __forceinline__ u16 f2bf(float f) {
    uint32 u = __builtin_bit_cast(uint32, f);
    u += 0x7fffu + ((u >> 16) & 1u);  // RNE
    return (u16)(u >> 16);
}
__device__ __forceinline__ uint32 pack2(float a, float b) {
    return (uint32)f2bf(a) | ((uint32)f2bf(b) << 16);
}
// biased-u8 dequant helpers: compiler emits v_cvt_f32_ubyte0..3
__device__ __forceinline__ float ub0(uint32 u) { return (float)(u & 255u); }
__device__ __forceinline__ float ub1(uint32 u) { return (float)((u >> 8) & 255u); }
__device__ __forceinline__ float ub2(uint32 u) { return (float)((u >> 16) & 255u); }
__device__ __forceinline__ float ub3(uint32 u) { return (float)(u >> 24); }

// async global->LDS, 16 B per lane, deposit at wave-uniform base + lane*16
#define GLOAD_LDS16(g, l)                                                                  \
    __builtin_amdgcn_global_load_lds((const __attribute__((address_space(1))) void*)(g),   \
                                     (__attribute__((address_space(3))) void*)(l), 16, 0, 0)

// ---------------- scans ----------------
#define SCAN_B 1024

// scan_final with inlined block-prefix of partials (nb <= 128)
__global__ void scan_final(const int* __restrict__ in, int n, const int* __restrict__ bsum,
                           int nb, int* __restrict__ out) {
    __shared__ int lds[SCAN_B];
    __shared__ int bpre[128];
    if (threadIdx.x < 128) bpre[threadIdx.x] = (threadIdx.x < nb) ? bsum[threadIdx.x] : 0;
    __syncthreads();
    for (int s = 1; s < 128; s <<= 1) {
        int v = (threadIdx.x < 128 && threadIdx.x >= s) ? bpre[threadIdx.x - s] : 0;
        __syncthreads();
        if (threadIdx.x < 128) bpre[threadIdx.x] += v;
        __syncthreads();
    }
    int base = (blockIdx.x > 0) ? bpre[blockIdx.x - 1] : 0;
    int i = blockIdx.x * SCAN_B + threadIdx.x;
    int v = (i < n) ? in[i] : 0;
    lds[threadIdx.x] = v;
    __syncthreads();
    for (int s = 1; s < SCAN_B; s <<= 1) {
        int t = (threadIdx.x >= s) ? lds[threadIdx.x - s] : 0;
        __syncthreads();
        lds[threadIdx.x] += t;
        __syncthreads();
    }
    if (i < n) out[i + 1] = lds[threadIdx.x] + base;
    if (i == 0) out[0] = 0;
}

// ---------------- bucketed CSR build ----------------

// hist + chunk-sum (bsum) via global atomics; bsum must be zeroed beforehand
__global__ __launch_bounds__(256) void hist_pass(const int* __restrict__ dst,
                                                 int* __restrict__ hist,
                                                 int* __restrict__ bsum) {
    __shared__ int lh[NB];
    int t = threadIdx.x, blk = blockIdx.x;
    if (t < NB) lh[t] = 0;
    __syncthreads();
#pragma unroll
    for (int k = 0; k < EPB / 256; ++k) {
        int e = blk * EPB + k * 256 + t;
        if (e < N_EDGES) atomicAdd(&lh[dst[e] >> BSHIFT], 1);
    }
    __syncthreads();
    if (t < NB) {
        int fi = t * NCHUNK + blk;
        hist[fi] = lh[t];
        atomicAdd(&bsum[fi >> 10], lh[t]);
    }
}

__global__ __launch_bounds__(256) void bin_pairs(const int* __restrict__ src,
                                                 const int* __restrict__ dst,
                                                 const int* __restrict__ histoff,
                                                 uint32* __restrict__ pairs) {
    __shared__ int lbase[NB];
    __shared__ int lcur[NB];
    int t = threadIdx.x, blk = blockIdx.x;
    if (t < NB) {
        lbase[t] = histoff[t * NCHUNK + blk];
        lcur[t] = 0;
    }
    __syncthreads();
#pragma unroll
    for (int k = 0; k < EPB / 256; ++k) {
        int e = blk * EPB + k * 256 + t;
        if (e < N_EDGES) {
            int d = dst[e], s = src[e];
            int b = d >> BSHIFT;
            int r = atomicAdd(&lcur[b], 1);
            pairs[lbase[b] + r] = (uint32)(d & (BNODES - 1)) | ((uint32)s << BSHIFT);
        }
    }
}

#define PCAP 16384

// per-bucket CSR finalize + dinv + fused x-quantization + batch count
__global__ __launch_bounds__(256) void bucket_csr(const uint32* __restrict__ pairs,
                                                  const int* __restrict__ histoff,
                                                  const float* __restrict__ x,
                                                  const int* __restrict__ batch,
                                                  int* __restrict__ offs,
                                                  int* __restrict__ csr,
                                                  float* __restrict__ dinv,
                                                  u16* __restrict__ q8x,
                                                  float* __restrict__ qsx,
                                                  int* __restrict__ gcnt) {
    __shared__ uint32 lp[PCAP];
    __shared__ int lcnt[BNODES];
    __shared__ int lcur[BNODES];
    __shared__ int psum[256];
    int t = threadIdx.x, b = blockIdx.x;
    int n0 = b << BSHIFT;
    int nn = min(BNODES, N_NODES - n0);
    lcnt[t] = 0;
    lcnt[t + 256] = 0;
    __syncthreads();
    int ebase = histoff[b * NCHUNK];
    int eend = (b == NB - 1) ? N_EDGES : histoff[(b + 1) * NCHUNK];
    for (int i = ebase + t; i < eend; i += 256) {
        uint32 p = pairs[i];
        int li = i - ebase;
        if (li < PCAP) lp[li] = p;
        atomicAdd(&lcnt[p & (BNODES - 1)], 1);
    }
    __syncthreads();
    int c0 = lcnt[2 * t], c1 = lcnt[2 * t + 1];
    if (2 * t < nn) dinv[n0 + 2 * t] = rsqrtf((float)(c0 + 1));
    if (2 * t + 1 < nn) dinv[n0 + 2 * t + 1] = rsqrtf((float)(c1 + 1));
    psum[t] = c0 + c1;
    __syncthreads();
    for (int s = 1; s < 256; s <<= 1) {
        int v = (t >= s) ? psum[t - s] : 0;
        __syncthreads();
        psum[t] += v;
        __syncthreads();
    }
    int ep = psum[t] - (c0 + c1);
    lcur[2 * t] = ep;
    lcur[2 * t + 1] = ep + c0;
    if (2 * t < nn) offs[n0 + 2 * t] = ebase + ep;
    if (2 * t + 1 < nn) offs[n0 + 2 * t + 1] = ebase + ep + c0;
    if (b == NB - 1 && t == 0) offs[N_NODES] = N_EDGES;
    __syncthreads();
    for (int i = ebase + t; i < eend; i += 256) {
        int li = i - ebase;
        uint32 p = (li < PCAP) ? lp[li] : pairs[i];
        int r = atomicAdd(&lcur[p & (BNODES - 1)], 1);
        csr[ebase + r] = (int)(p >> BSHIFT);
    }
    // fused x quantization + batch count for this bucket's nodes (lcnt is stable)
    int lane = t & 63, wv = t >> 6;
    for (int i = wv; i < nn; i += 4) {
        int node = n0 + i;
        float d = rsqrtf((float)(lcnt[i] + 1));
        float2 v = *(const float2*)&x[(size_t)node * F0 + lane * 2];
        float f0 = v.x * d, f1 = v.y * d;
        float m = fmaxf(fabsf(f0), fabsf(f1));
        for (int s = 32; s > 0; s >>= 1) m = fmaxf(m, __shfl_xor(m, s, 64));
        float inv = (m > 0.f) ? 127.f / m : 0.f;
        int u0 = (int)rintf(f0 * inv) + 128, u1 = (int)rintf(f1 * inv) + 128;
        q8x[(size_t)node * 64 + lane] = (u16)((u0 & 255) | ((u1 & 255) << 8));
        if (lane == 0) {
            qsx[node] = m * (1.f / 127.f);
            atomicAdd(&gcnt[batch[node]], 1);
        }
    }
}

// ---------------- weight transpose+cast ----------------

__global__ void transpose_w2(const float* __restrict__ W1, const float* __restrict__ W2,
                             u16* __restrict__ W1t, u16* __restrict__ W2t) {
    int id = blockIdx.x * blockDim.x + threadIdx.x;
    if (id < F0 * F1) {
        int k = id / F1, n = id % F1;
        W1t[(size_t)n * F0 + k] = f2bf(W1[id]);
    } else {
        int id2 = id - F0 * F1;
        if (id2 < F1 * F1) {
            int k = id2 / F1, n = id2 % F1;
            W2t[(size_t)n * F1 + k] = f2bf(W2[id2]);
        }
    }
}

// ---------------- biased-u8 gather aggregation (standalone, high occupancy) ----------------
// deq(j) = (u8 - 128)*qs[j] = h[j]*dinv[j];
// out[i] = bf16( dinv[i] * (sum_j deq(j) + deq(i)) ), via acc - 128*sum(scales)

template <int F>
__global__ __launch_bounds__(256) void aggregate_q8(const void* __restrict__ q8,
                                                    const float* __restrict__ qs,
                                                    const int* __restrict__ offs,
                                                    const int* __restrict__ csr,
                                                    const float* __restrict__ dinv,
                                                    u16* __restrict__ out) {
    constexpr int V = F / 64;
    int node = blockIdx.x * 4 + (threadIdx.x >> 6);
    if (node >= N_NODES) return;
    int lane = threadIdx.x & 63;
    float acc[V];
    float ssum;
    {
        float s = qs[node];
        ssum = s;
        if constexpr (V == 2) {
            uint32 q = (uint32)((const u16*)q8)[(size_t)node * 64 + lane];
            acc[0] = ub0(q) * s;
            acc[1] = ub1(q) * s;
        } else {
            uint32 q = ((const uint32*)q8)[(size_t)node * 64 + lane];
            acc[0] = ub0(q) * s;
            acc[1] = ub1(q) * s;
            acc[2] = ub2(q) * s;
            acc[3] = ub3(q) * s;
        }
    }
    int e0 = offs[node], e1 = offs[node + 1];
    for (int b = e0; b < e1; b += 64) {
        bool valid = (b + lane) < e1;
        int idx = valid ? csr[b + lane] : 0;
        float sv = valid ? qs[idx] : 0.f;
        int cnt = min(64, e1 - b);
        int t = 0;
        // 8-deep row pipeline
        for (; t + 8 <= cnt; t += 8) {
            int j[8];
            float s[8];
#pragma unroll
            for (int u = 0; u < 8; ++u) {
                j[u] = __shfl(idx, t + u);
                s[u] = __shfl(sv, t + u);
            }
            uint32 a[8];
#pragma unroll
            for (int u = 0; u < 8; ++u) {
                if constexpr (V == 2)
                    a[u] = (uint32)((const u16*)q8)[(size_t)j[u] * 64 + lane];
                else
                    a[u] = ((const uint32*)q8)[(size_t)j[u] * 64 + lane];
            }
#pragma unroll
            for (int u = 0; u < 8; ++u) {
                ssum += s[u];
                acc[0] += ub0(a[u]) * s[u];
                acc[1] += ub1(a[u]) * s[u];
                if constexpr (V == 4) {
                    acc[2] += ub2(a[u]) * s[u];
                    acc[3] += ub3(a[u]) * s[u];
                }
            }
        }
        for (; t < cnt; ++t) {
            int j0 = __shfl(idx, t);
            float s0 = __shfl(sv, t);
            ssum += s0;
            uint32 a;
            if constexpr (V == 2)
                a = (uint32)((const u16*)q8)[(size_t)j0 * 64 + lane];
            else
                a = ((const uint32*)q8)[(size_t)j0 * 64 + lane];
            acc[0] += ub0(a) * s0;
            acc[1] += ub1(a) * s0;
            if constexpr (V == 4) {
                acc[2] += ub2(a) * s0;
                acc[3] += ub3(a) * s0;
            }
        }
    }
    float di = dinv[node];
    float bb = 128.f * ssum;
    u16* orow = out + (size_t)node * F + lane * V;
    if constexpr (V == 2) {
        *(uint32*)orow = pack2((acc[0] - bb) * di, (acc[1] - bb) * di);
    } else {
        uint2 o;
        o.x = pack2((acc[0] - bb) * di, (acc[1] - bb) * di);
        o.y = pack2((acc[2] - bb) * di, (acc[3] - bb) * di);
        *(uint2*)orow = o;
    }
}

// ---------------- bf16 MFMA GEMM, BM=64 x BN=256, global_load_lds staging ----------------
// A rows read unguarded (caller pads A by >=64 rows).
// QUANT=true : epilogue = bias+relu, *dinv, row-absmax -> biased-u8 q8 + fp32 qs
// QUANT=false: epilogue = bias+relu -> fused mean-pool atomics into gpool

template <int K, bool QUANT>
__global__ __launch_bounds__(256) void gemm_fused(const u16* __restrict__ A,
                                                  const u16* __restrict__ Bt,
                                                  const float* __restrict__ bias,
                                                  const float* __restrict__ dinv,
                                                  int M,
                                                  uint32* __restrict__ q8,
                                                  float* __restrict__ qs,
                                                  const int* __restrict__ batch,
                                                  float* __restrict__ gpool) {
    constexpr int BM = 64, BN = 256, BK = 64;
    __shared__ __align__(16) char smem[40960];
    u16* As = (u16*)smem;
    u16* Bs = (u16*)smem + BM * BK;
    int tid = threadIdx.x;
    int lane = tid & 63;
    int wid = __builtin_amdgcn_readfirstlane(tid >> 6);
    int row0 = blockIdx.x * BM;
    int lr = lane & 15, lq = lane >> 4;
    int wn = wid * 64;
    int srow = lane >> 3;
    int schunk = (lane & 7) * 8;

    f32x4 acc[4][4];
#pragma unroll
    for (int i = 0; i < 4; ++i)
#pragma unroll
        for (int j = 0; j < 4; ++j) acc[i][j] = (f32x4){0.f, 0.f, 0.f, 0.f};

    for (int k0 = 0; k0 < K; k0 += BK) {
#pragma unroll
        for (int p = 0; p < 2; ++p) {
            int r0 = wid * 16 + p * 8;
            const u16* g = A + (size_t)(row0 + r0 + srow) * K + k0 + schunk;
            GLOAD_LDS16(g, As + r0 * BK);
        }
#pragma unroll
        for (int p = 0; p < 8; ++p) {
            int r0 = wid * 64 + p * 8;
            const u16* g = Bt + (size_t)(r0 + srow) * K + k0 + schunk;
            GLOAD_LDS16(g, Bs + r0 * BK);
        }
        __syncthreads();
#pragma unroll
        for (int kk = 0; kk < BK; kk += 32) {
            bf16x8 af[4], bfr[4];
#pragma unroll
            for (int i = 0; i < 4; ++i)
                af[i] = __builtin_bit_cast(bf16x8, *(const u16x8*)&As[(i * 16 + lr) * BK + kk + lq * 8]);
#pragma unroll
            for (int j = 0; j < 4; ++j)
                bfr[j] = __builtin_bit_cast(bf16x8, *(const u16x8*)&Bs[(wn + j * 16 + lr) * BK + kk + lq * 8]);
#pragma unroll
            for (int i = 0; i < 4; ++i)
#pragma unroll
                for (int j = 0; j < 4; ++j)
                    acc[i][j] = __builtin_amdgcn_mfma_f32_16x16x32_bf16(af[i], bfr[j], acc[i][j], 0, 0, 0);
        }
        __syncthreads();
    }

    // epilogue tile P[64][260] bf16 (overlays As/Bs)
    u16(*P)[260] = (u16(*)[260])smem;
#pragma unroll
    for (int i = 0; i < 4; ++i) {
#pragma unroll
        for (int j = 0; j < 4; ++j) {
            int cl = wn + j * 16 + lr;
            float bv = bias[cl];
#pragma unroll
            for (int r = 0; r < 4; ++r) {
                int rl = i * 16 + lq * 4 + r;
                int row = row0 + rl;
                float v = 0.f;
                if (row < M) {
                    v = fmaxf(acc[i][j][r] + bv, 0.f);
                    if constexpr (QUANT) v *= dinv[row];
                }
                P[rl][cl] = f2bf(v);
            }
        }
    }

    if constexpr (QUANT) {
        float* rmax = (float*)(smem + 33280);  // [4][64]
        __syncthreads();
        int row = tid & 63, q = tid >> 6;
        float m = 0.f;
#pragma unroll 8
        for (int i = 0; i < 64; ++i) m = fmaxf(m, b16f(P[row][q * 64 + i]));  // post-relu >= 0
        rmax[q * 64 + row] = m;
        __syncthreads();
        m = fmaxf(fmaxf(rmax[row], rmax[64 + row]), fmaxf(rmax[128 + row], rmax[192 + row]));
        int gr = row0 + row;
        if (gr < M) {
            float inv = (m > 0.f) ? 127.f / m : 0.f;
#pragma unroll
            for (int d = 0; d < 16; d += 4) {
                uint32 dw[4];
#pragma unroll
                for (int e = 0; e < 4; ++e) {
                    int cb = q * 64 + (d + e) * 4;
                    uint32 v0 = (uint32)((int)rintf(b16f(P[row][cb + 0]) * inv) + 128);
                    uint32 v1 = (uint32)((int)rintf(b16f(P[row][cb + 1]) * inv) + 128);
                    uint32 v2 = (uint32)((int)rintf(b16f(P[row][cb + 2]) * inv) + 128);
                    uint32 v3 = (uint32)((int)rintf(b16f(P[row][cb + 3]) * inv) + 128);
                    dw[e] = v0 | (v1 << 8) | (v2 << 16) | (v3 << 24);
                }
                *(uint4*)&q8[(size_t)gr * 64 + q * 16 + d] = make_uint4(dw[0], dw[1], dw[2], dw[3]);
            }
            if (q == 0) qs[gr] = m * (1.f / 127.f);
        }
    } else {
        int* batchl = (int*)(smem + 33280);  // [64]
        if (tid < BM) {
            int row = row0 + tid;
            batchl[tid] = batch[row < M ? row : (M - 1)];
        }
        __syncthreads();
        int c = tid;  // one column per thread
        int nrows = min(BM, M - row0);
        int cur = batchl[0];
        float sum = 0.f;
        for (int r = 0; r < nrows; ++r) {
            int gb = batchl[r];
            float v = b16f(P[r][c]);
            if (gb != cur) {
                atomicAdd(&gpool[(size_t)cur * BN + c], sum);
                sum = 0.f;
                cur = gb;
            }
            sum += v;
        }
        atomicAdd(&gpool[(size_t)cur * BN + c], sum);
    }
}

// ---------------- classifier + log_softmax ----------------

__global__ void classify(const float* __restrict__ gpool, const int* __restrict__ gcnt,
                         const float* __restrict__ Wc, const float* __restrict__ bc,
                         float* __restrict__ out) {
    int gr = blockIdx.x;
    int c = threadIdx.x;  // 0..63, single wave
    __shared__ float gl[F1];
    float inv = 1.f / fmaxf((float)gcnt[gr], 1.f);
    for (int k = c; k < F1; k += 64) gl[k] = gpool[(size_t)gr * F1 + k] * inv;
    __syncthreads();
    float acc = bc[c];
    for (int k = 0; k < F1; ++k) acc += gl[k] * Wc[k * NCLS + c];
    float m = acc;
    for (int s = 32; s > 0; s >>= 1) m = fmaxf(m, __shfl_xor(m, s, 64));
    float ex = __expf(acc - m);
    float sum = ex;
    for (int s = 32; s > 0; s >>= 1) sum += __shfl_xor(sum, s, 64);
    out[(size_t)gr * NCLS + c] = acc - m - __logf(sum);
}

// ---------------- launch ----------------

extern "C" void kernel_launch(void* const* d_in, const int* in_sizes, int n_in,
                              void* d_out, int out_size, void* d_ws, size_t ws_size,
                              hipStream_t stream) {
    const float* x = (const float*)d_in[0];
    const int* ei = (const int*)d_in[1];
    const int* batch = (const int*)d_in[2];
    const float* W1 = (const float*)d_in[3];
    const float* b1 = (const float*)d_in[4];
    const float* W2 = (const float*)d_in[5];
    const float* b2 = (const float*)d_in[6];
    const float* Wc = (const float*)d_in[7];
    const float* bc = (const float*)d_in[8];
    float* out = (float*)d_out;
    const int* src = ei;
    const int* dst = ei + N_EDGES;

    char* w = (char*)d_ws;
    auto take = [&](size_t n) { char* p = w; w += (n + 255) & ~(size_t)255; return p; };
    // contiguous zero-init region: gcnt | bsum | gpool (all sizes multiple of 256)
    int* gcnt = (int*)take((size_t)N_GRAPHS * 4);
    int* bsum = (int*)take((size_t)1024 * 4);
    float* gpool = (float*)take((size_t)N_GRAPHS * F1 * 4);
    size_t zspan = (size_t)N_GRAPHS * 4 + 1024 * 4 + (size_t)N_GRAPHS * F1 * 4;

    float* dinv = (float*)take((size_t)N_NODES * 4);
    int* offs = (int*)take((size_t)(N_NODES + 1) * 4);
    int* hist = (int*)take((size_t)FLATN * 4);
    int* histoff = (int*)take((size_t)(FLATN + 1) * 4);
    uint32* pairs = (uint32*)take((size_t)N_EDGES * 4);
    int* csr = (int*)take((size_t)N_EDGES * 4);
    u16* q8x = (u16*)take((size_t)N_NODES * 64 * 2);        // biased u8 x*dinv rows (128 B/row)
    float* qsx = (float*)take((size_t)N_NODES * 4);
    uint32* q8h = (uint32*)take((size_t)N_NODES * 64 * 4);  // biased u8 h1*dinv rows (256 B/row)
    float* qsh = (float*)take((size_t)N_NODES * 4);
    u16* aggx = (u16*)take((size_t)(N_NODES + 64) * F0 * 2);  // bf16, +64 rows GEMM overread pad
    u16* agg1 = (u16*)take((size_t)(N_NODES + 64) * F1 * 2);  // bf16, +64 rows pad
    u16* W1t = (u16*)take((size_t)F0 * F1 * 2);
    u16* W2t = (u16*)take((size_t)F1 * F1 * 2);

    hipMemsetAsync(gcnt, 0, zspan, stream);

    // CSR build: hist(+bsum) -> scan_final -> bin -> per-bucket finalize
    // (deg/dinv/offs/csr + fused x-quant + batch count)
    hist_pass<<<NCHUNK, 256, 0, stream>>>(dst, hist, bsum);
    {
        int nb = (FLATN + SCAN_B - 1) / SCAN_B;  // 75
        scan_final<<<nb, SCAN_B, 0, stream>>>(hist, FLATN, bsum, nb, histoff);
    }
    bin_pairs<<<NCHUNK, 256, 0, stream>>>(src, dst, histoff, pairs);
    bucket_csr<<<NB, 256, 0, stream>>>(pairs, histoff, x, batch, offs, csr, dinv, q8x, qsx, gcnt);

    transpose_w2<<<(F0 * F1 + F1 * F1 + 255) / 256, 256, 0, stream>>>(W1, W2, W1t, W2t);

    int mblocks = (N_NODES + 63) / 64;  // 1563

    // conv1: u8 gather-aggregate -> bf16, MFMA GEMM (+b1, relu, *dinv) + fused quantize -> q8h
    aggregate_q8<F0><<<(N_NODES + 3) / 4, 256, 0, stream>>>(q8x, qsx, offs, csr, dinv, aggx);
    gemm_fused<F0, true><<<mblocks, 256, 0, stream>>>(aggx, W1t, b1, dinv, N_NODES,
                                                      q8h, qsh, nullptr, nullptr);

    // conv2: u8 gather-aggregate -> bf16, MFMA GEMM (+b2, relu) + fused mean-pool
    aggregate_q8<F1><<<(N_NODES + 3) / 4, 256, 0, stream>>>(q8h, qsh, offs, csr, dinv, agg1);
    gemm_fused<F1, false><<<mblocks, 256, 0, stream>>>(agg1, W2t, b2, dinv, N_NODES,
                                                       nullptr, nullptr, batch, gpool);

    // classifier + log_softmax
    classify<<<N_GRAPHS, 64, 0, stream>>>(gpool, gcnt, Wc, bc, out);
}

// Round 10
// 573.692 us; speedup vs baseline: 1.1244x; 1.1244x over previous
//
#include <hip/hip_runtime.h>
#include <hip/hip_bf16.h>

#define N_NODES 100000
#define N_EDGES 1600000
#define N_GRAPHS 2048
#define F0 128
#define F1 256
#define NCLS 64

// bucketed CSR build
#define BSHIFT 9
#define BNODES 512
#define NB 196
#define EPB 4096
#define NCHUNK 391
#define FLATN (NB * NCHUNK)

typedef unsigned int uint32;
typedef unsigned short u16;
typedef u16 u16x8 __attribute__((ext_vector_type(8)));
typedef __bf16 bf16x8 __attribute__((ext_vector_type(8)));
typedef float f32x4 __attribute__((ext_vector_type(4)));

__device__ __forceinline__ float b16f(u16 v) { return __builtin_bit_cast(float, (uint32)v << 16); }
__device__ __forceinline__ u16 f2bf(float f) {
    uint32 u = __builtin_bit_cast(uint32, f);
    u += 0x7fffu + ((u >> 16) & 1u);  // RNE
    return (u16)(u >> 16);
}
__device__ __forceinline__ uint32 pack2(float a, float b) {
    return (uint32)f2bf(a) | ((uint32)f2bf(b) << 16);
}
// biased-u8 dequant helpers: compiler emits v_cvt_f32_ubyte0..3
__device__ __forceinline__ float ub0(uint32 u) { return (float)(u & 255u); }
__device__ __forceinline__ float ub1(uint32 u) { return (float)((u >> 8) & 255u); }
__device__ __forceinline__ float ub2(uint32 u) { return (float)((u >> 16) & 255u); }
__device__ __forceinline__ float ub3(uint32 u) { return (float)(u >> 24); }

// async global->LDS, 16 B per lane, deposit at wave-uniform base + lane*16
#define GLOAD_LDS16(g, l)                                                                  \
    __builtin_amdgcn_global_load_lds((const __attribute__((address_space(1))) void*)(g),   \
                                     (__attribute__((address_space(3))) void*)(l), 16, 0, 0)

// ---------------- scans ----------------
#define SCAN_B 1024

// scan_final with inlined block-prefix of partials (nb <= 128)
__global__ void scan_final(const int* __restrict__ in, int n, const int* __restrict__ bsum,
                           int nb, int* __restrict__ out) {
    __shared__ int lds[SCAN_B];
    __shared__ int bpre[128];
    if (threadIdx.x < 128) bpre[threadIdx.x] = (threadIdx.x < nb) ? bsum[threadIdx.x] : 0;
    __syncthreads();
    for (int s = 1; s < 128; s <<= 1) {
        int v = (threadIdx.x < 128 && threadIdx.x >= s) ? bpre[threadIdx.x - s] : 0;
        __syncthreads();
        if (threadIdx.x < 128) bpre[threadIdx.x] += v;
        __syncthreads();
    }
    int base = (blockIdx.x > 0) ? bpre[blockIdx.x - 1] : 0;
    int i = blockIdx.x * SCAN_B + threadIdx.x;
    int v = (i < n) ? in[i] : 0;
    lds[threadIdx.x] = v;
    __syncthreads();
    for (int s = 1; s < SCAN_B; s <<= 1) {
        int t = (threadIdx.x >= s) ? lds[threadIdx.x - s] : 0;
        __syncthreads();
        lds[threadIdx.x] += t;
        __syncthreads();
    }
    if (i < n) out[i + 1] = lds[threadIdx.x] + base;
    if (i == 0) out[0] = 0;
}

// ---------------- bucketed CSR build ----------------

// hist + chunk-sum (bsum) via global atomics; bsum must be zeroed beforehand
__global__ __launch_bounds__(256) void hist_pass(const int* __restrict__ dst,
                                                 int* __restrict__ hist,
                                                 int* __restrict__ bsum) {
    __shared__ int lh[NB];
    int t = threadIdx.x, blk = blockIdx.x;
    if (t < NB) lh[t] = 0;
    __syncthreads();
#pragma unroll
    for (int k = 0; k < EPB / 256; ++k) {
        int e = blk * EPB + k * 256 + t;
        if (e < N_EDGES) atomicAdd(&lh[dst[e] >> BSHIFT], 1);
    }
    __syncthreads();
    if (t < NB) {
        int fi = t * NCHUNK + blk;
        hist[fi] = lh[t];
        atomicAdd(&bsum[fi >> 10], lh[t]);
    }
}

__global__ __launch_bounds__(256) void bin_pairs(const int* __restrict__ src,
                                                 const int* __restrict__ dst,
                                                 const int* __restrict__ histoff,
                                                 uint32* __restrict__ pairs) {
    __shared__ int lbase[NB];
    __shared__ int lcur[NB];
    int t = threadIdx.x, blk = blockIdx.x;
    if (t < NB) {
        lbase[t] = histoff[t * NCHUNK + blk];
        lcur[t] = 0;
    }
    __syncthreads();
#pragma unroll
    for (int k = 0; k < EPB / 256; ++k) {
        int e = blk * EPB + k * 256 + t;
        if (e < N_EDGES) {
            int d = dst[e], s = src[e];
            int b = d >> BSHIFT;
            int r = atomicAdd(&lcur[b], 1);
            pairs[lbase[b] + r] = (uint32)(d & (BNODES - 1)) | ((uint32)s << BSHIFT);
        }
    }
}

#define PCAP 16384

// per-bucket CSR finalize: deg->dinv, offs, csr (CSR work only; high-throughput work stays out)
__global__ __launch_bounds__(256) void bucket_csr(const uint32* __restrict__ pairs,
                                                  const int* __restrict__ histoff,
                                                  int* __restrict__ offs,
                                                  int* __restrict__ csr,
                                                  float* __restrict__ dinv) {
    __shared__ uint32 lp[PCAP];
    __shared__ int lcnt[BNODES];
    __shared__ int lcur[BNODES];
    __shared__ int psum[256];
    int t = threadIdx.x, b = blockIdx.x;
    int n0 = b << BSHIFT;
    int nn = min(BNODES, N_NODES - n0);
    lcnt[t] = 0;
    lcnt[t + 256] = 0;
    __syncthreads();
    int ebase = histoff[b * NCHUNK];
    int eend = (b == NB - 1) ? N_EDGES : histoff[(b + 1) * NCHUNK];
    for (int i = ebase + t; i < eend; i += 256) {
        uint32 p = pairs[i];
        int li = i - ebase;
        if (li < PCAP) lp[li] = p;
        atomicAdd(&lcnt[p & (BNODES - 1)], 1);
    }
    __syncthreads();
    int c0 = lcnt[2 * t], c1 = lcnt[2 * t + 1];
    if (2 * t < nn) dinv[n0 + 2 * t] = rsqrtf((float)(c0 + 1));
    if (2 * t + 1 < nn) dinv[n0 + 2 * t + 1] = rsqrtf((float)(c1 + 1));
    psum[t] = c0 + c1;
    __syncthreads();
    for (int s = 1; s < 256; s <<= 1) {
        int v = (t >= s) ? psum[t - s] : 0;
        __syncthreads();
        psum[t] += v;
        __syncthreads();
    }
    int ep = psum[t] - (c0 + c1);
    lcur[2 * t] = ep;
    lcur[2 * t + 1] = ep + c0;
    if (2 * t < nn) offs[n0 + 2 * t] = ebase + ep;
    if (2 * t + 1 < nn) offs[n0 + 2 * t + 1] = ebase + ep + c0;
    if (b == NB - 1 && t == 0) offs[N_NODES] = N_EDGES;
    __syncthreads();
    for (int i = ebase + t; i < eend; i += 256) {
        int li = i - ebase;
        uint32 p = (li < PCAP) ? lp[li] : pairs[i];
        int r = atomicAdd(&lcur[p & (BNODES - 1)], 1);
        csr[ebase + r] = (int)(p >> BSHIFT);
    }
}

// ---------------- quantize x: biased u8 row + fp32 scale; fuses count_batch ----------------
// standalone at 25k blocks: this work needs full-device occupancy (R9 lesson)

__global__ __launch_bounds__(256) void cast_q8_x(const float* __restrict__ x,
                                                 const float* __restrict__ dinv,
                                                 const int* __restrict__ batch,
                                                 u16* __restrict__ q8,
                                                 float* __restrict__ qs,
                                                 int* __restrict__ gcnt) {
    int node = blockIdx.x * 4 + (threadIdx.x >> 6);
    if (node >= N_NODES) return;
    int lane = threadIdx.x & 63;
    float d = dinv[node];
    float2 v = *(const float2*)&x[(size_t)node * F0 + lane * 2];
    float f0 = v.x * d, f1 = v.y * d;
    float m = fmaxf(fabsf(f0), fabsf(f1));
    for (int s = 32; s > 0; s >>= 1) m = fmaxf(m, __shfl_xor(m, s, 64));
    float inv = (m > 0.f) ? 127.f / m : 0.f;
    int u0 = (int)rintf(f0 * inv) + 128, u1 = (int)rintf(f1 * inv) + 128;
    q8[(size_t)node * 64 + lane] = (u16)((u0 & 255) | ((u1 & 255) << 8));
    if (lane == 0) {
        qs[node] = m * (1.f / 127.f);
        atomicAdd(&gcnt[batch[node]], 1);
    }
}

// ---------------- weight transpose+cast ----------------

__global__ void transpose_w2(const float* __restrict__ W1, const float* __restrict__ W2,
                             u16* __restrict__ W1t, u16* __restrict__ W2t) {
    int id = blockIdx.x * blockDim.x + threadIdx.x;
    if (id < F0 * F1) {
        int k = id / F1, n = id % F1;
        W1t[(size_t)n * F0 + k] = f2bf(W1[id]);
    } else {
        int id2 = id - F0 * F1;
        if (id2 < F1 * F1) {
            int k = id2 / F1, n = id2 % F1;
            W2t[(size_t)n * F1 + k] = f2bf(W2[id2]);
        }
    }
}

// ---------------- biased-u8 gather aggregation (standalone, high occupancy) ----------------
// deq(j) = (u8 - 128)*qs[j] = h[j]*dinv[j];
// out[i] = bf16( dinv[i] * (sum_j deq(j) + deq(i)) ), via acc - 128*sum(scales)

template <int F>
__global__ __launch_bounds__(256) void aggregate_q8(const void* __restrict__ q8,
                                                    const float* __restrict__ qs,
                                                    const int* __restrict__ offs,
                                                    const int* __restrict__ csr,
                                                    const float* __restrict__ dinv,
                                                    u16* __restrict__ out) {
    constexpr int V = F / 64;
    int node = blockIdx.x * 4 + (threadIdx.x >> 6);
    if (node >= N_NODES) return;
    int lane = threadIdx.x & 63;
    float acc[V];
    float ssum;
    {
        float s = qs[node];
        ssum = s;
        if constexpr (V == 2) {
            uint32 q = (uint32)((const u16*)q8)[(size_t)node * 64 + lane];
            acc[0] = ub0(q) * s;
            acc[1] = ub1(q) * s;
        } else {
            uint32 q = ((const uint32*)q8)[(size_t)node * 64 + lane];
            acc[0] = ub0(q) * s;
            acc[1] = ub1(q) * s;
            acc[2] = ub2(q) * s;
            acc[3] = ub3(q) * s;
        }
    }
    int e0 = offs[node], e1 = offs[node + 1];
    for (int b = e0; b < e1; b += 64) {
        bool valid = (b + lane) < e1;
        int idx = valid ? csr[b + lane] : 0;
        float sv = valid ? qs[idx] : 0.f;
        int cnt = min(64, e1 - b);
        int t = 0;
        // 8-deep row pipeline
        for (; t + 8 <= cnt; t += 8) {
            int j[8];
            float s[8];
#pragma unroll
            for (int u = 0; u < 8; ++u) {
                j[u] = __shfl(idx, t + u);
                s[u] = __shfl(sv, t + u);
            }
            uint32 a[8];
#pragma unroll
            for (int u = 0; u < 8; ++u) {
                if constexpr (V == 2)
                    a[u] = (uint32)((const u16*)q8)[(size_t)j[u] * 64 + lane];
                else
                    a[u] = ((const uint32*)q8)[(size_t)j[u] * 64 + lane];
            }
#pragma unroll
            for (int u = 0; u < 8; ++u) {
                ssum += s[u];
                acc[0] += ub0(a[u]) * s[u];
                acc[1] += ub1(a[u]) * s[u];
                if constexpr (V == 4) {
                    acc[2] += ub2(a[u]) * s[u];
                    acc[3] += ub3(a[u]) * s[u];
                }
            }
        }
        for (; t < cnt; ++t) {
            int j0 = __shfl(idx, t);
            float s0 = __shfl(sv, t);
            ssum += s0;
            uint32 a;
            if constexpr (V == 2)
                a = (uint32)((const u16*)q8)[(size_t)j0 * 64 + lane];
            else
                a = ((const uint32*)q8)[(size_t)j0 * 64 + lane];
            acc[0] += ub0(a) * s0;
            acc[1] += ub1(a) * s0;
            if constexpr (V == 4) {
                acc[2] += ub2(a) * s0;
                acc[3] += ub3(a) * s0;
            }
        }
    }
    float di = dinv[node];
    float bb = 128.f * ssum;
    u16* orow = out + (size_t)node * F + lane * V;
    if constexpr (V == 2) {
        *(uint32*)orow = pack2((acc[0] - bb) * di, (acc[1] - bb) * di);
    } else {
        uint2 o;
        o.x = pack2((acc[0] - bb) * di, (acc[1] - bb) * di);
        o.y = pack2((acc[2] - bb) * di, (acc[3] - bb) * di);
        *(uint2*)orow = o;
    }
}

// ---------------- bf16 MFMA GEMM, BM=64 x BN=256, global_load_lds staging ----------------
// A rows read unguarded (caller pads A by >=64 rows).
// QUANT=true : epilogue = bias+relu, *dinv, row-absmax -> biased-u8 q8 + fp32 qs
// QUANT=false: epilogue = bias+relu -> fused mean-pool atomics into gpool

template <int K, bool QUANT>
__global__ __launch_bounds__(256) void gemm_fused(const u16* __restrict__ A,
                                                  const u16* __restrict__ Bt,
                                                  const float* __restrict__ bias,
                                                  const float* __restrict__ dinv,
                                                  int M,
                                                  uint32* __restrict__ q8,
                                                  float* __restrict__ qs,
                                                  const int* __restrict__ batch,
                                                  float* __restrict__ gpool) {
    constexpr int BM = 64, BN = 256, BK = 64;
    __shared__ __align__(16) char smem[40960];
    u16* As = (u16*)smem;
    u16* Bs = (u16*)smem + BM * BK;
    int tid = threadIdx.x;
    int lane = tid & 63;
    int wid = __builtin_amdgcn_readfirstlane(tid >> 6);
    int row0 = blockIdx.x * BM;
    int lr = lane & 15, lq = lane >> 4;
    int wn = wid * 64;
    int srow = lane >> 3;
    int schunk = (lane & 7) * 8;

    f32x4 acc[4][4];
#pragma unroll
    for (int i = 0; i < 4; ++i)
#pragma unroll
        for (int j = 0; j < 4; ++j) acc[i][j] = (f32x4){0.f, 0.f, 0.f, 0.f};

    for (int k0 = 0; k0 < K; k0 += BK) {
#pragma unroll
        for (int p = 0; p < 2; ++p) {
            int r0 = wid * 16 + p * 8;
            const u16* g = A + (size_t)(row0 + r0 + srow) * K + k0 + schunk;
            GLOAD_LDS16(g, As + r0 * BK);
        }
#pragma unroll
        for (int p = 0; p < 8; ++p) {
            int r0 = wid * 64 + p * 8;
            const u16* g = Bt + (size_t)(r0 + srow) * K + k0 + schunk;
            GLOAD_LDS16(g, Bs + r0 * BK);
        }
        __syncthreads();
#pragma unroll
        for (int kk = 0; kk < BK; kk += 32) {
            bf16x8 af[4], bfr[4];
#pragma unroll
            for (int i = 0; i < 4; ++i)
                af[i] = __builtin_bit_cast(bf16x8, *(const u16x8*)&As[(i * 16 + lr) * BK + kk + lq * 8]);
#pragma unroll
            for (int j = 0; j < 4; ++j)
                bfr[j] = __builtin_bit_cast(bf16x8, *(const u16x8*)&Bs[(wn + j * 16 + lr) * BK + kk + lq * 8]);
#pragma unroll
            for (int i = 0; i < 4; ++i)
#pragma unroll
                for (int j = 0; j < 4; ++j)
                    acc[i][j] = __builtin_amdgcn_mfma_f32_16x16x32_bf16(af[i], bfr[j], acc[i][j], 0, 0, 0);
        }
        __syncthreads();
    }

    // epilogue tile P[64][260] bf16 (overlays As/Bs)
    u16(*P)[260] = (u16(*)[260])smem;
#pragma unroll
    for (int i = 0; i < 4; ++i) {
#pragma unroll
        for (int j = 0; j < 4; ++j) {
            int cl = wn + j * 16 + lr;
            float bv = bias[cl];
#pragma unroll
            for (int r = 0; r < 4; ++r) {
                int rl = i * 16 + lq * 4 + r;
                int row = row0 + rl;
                float v = 0.f;
                if (row < M) {
                    v = fmaxf(acc[i][j][r] + bv, 0.f);
                    if constexpr (QUANT) v *= dinv[row];
                }
                P[rl][cl] = f2bf(v);
            }
        }
    }

    if constexpr (QUANT) {
        float* rmax = (float*)(smem + 33280);  // [4][64]
        __syncthreads();
        int row = tid & 63, q = tid >> 6;
        float m = 0.f;
#pragma unroll 8
        for (int i = 0; i < 64; ++i) m = fmaxf(m, b16f(P[row][q * 64 + i]));  // post-relu >= 0
        rmax[q * 64 + row] = m;
        __syncthreads();
        m = fmaxf(fmaxf(rmax[row], rmax[64 + row]), fmaxf(rmax[128 + row], rmax[192 + row]));
        int gr = row0 + row;
        if (gr < M) {
            float inv = (m > 0.f) ? 127.f / m : 0.f;
#pragma unroll
            for (int d = 0; d < 16; d += 4) {
                uint32 dw[4];
#pragma unroll
                for (int e = 0; e < 4; ++e) {
                    int cb = q * 64 + (d + e) * 4;
                    uint32 v0 = (uint32)((int)rintf(b16f(P[row][cb + 0]) * inv) + 128);
                    uint32 v1 = (uint32)((int)rintf(b16f(P[row][cb + 1]) * inv) + 128);
                    uint32 v2 = (uint32)((int)rintf(b16f(P[row][cb + 2]) * inv) + 128);
                    uint32 v3 = (uint32)((int)rintf(b16f(P[row][cb + 3]) * inv) + 128);
                    dw[e] = v0 | (v1 << 8) | (v2 << 16) | (v3 << 24);
                }
                *(uint4*)&q8[(size_t)gr * 64 + q * 16 + d] = make_uint4(dw[0], dw[1], dw[2], dw[3]);
            }
            if (q == 0) qs[gr] = m * (1.f / 127.f);
        }
    } else {
        int* batchl = (int*)(smem + 33280);  // [64]
        if (tid < BM) {
            int row = row0 + tid;
            batchl[tid] = batch[row < M ? row : (M - 1)];
        }
        __syncthreads();
        int c = tid;  // one column per thread
        int nrows = min(BM, M - row0);
        int cur = batchl[0];
        float sum = 0.f;
        for (int r = 0; r < nrows; ++r) {
            int gb = batchl[r];
            float v = b16f(P[r][c]);
            if (gb != cur) {
                atomicAdd(&gpool[(size_t)cur * BN + c], sum);
                sum = 0.f;
                cur = gb;
            }
            sum += v;
        }
        atomicAdd(&gpool[(size_t)cur * BN + c], sum);
    }
}

// ---------------- classifier + log_softmax ----------------

__global__ void classify(const float* __restrict__ gpool, const int* __restrict__ gcnt,
                         const float* __restrict__ Wc, const float* __restrict__ bc,
                         float* __restrict__ out) {
    int gr = blockIdx.x;
    int c = threadIdx.x;  // 0..63, single wave
    __shared__ float gl[F1];
    float inv = 1.f / fmaxf((float)gcnt[gr], 1.f);
    for (int k = c; k < F1; k += 64) gl[k] = gpool[(size_t)gr * F1 + k] * inv;
    __syncthreads();
    float acc = bc[c];
    for (int k = 0; k < F1; ++k) acc += gl[k] * Wc[k * NCLS + c];
    float m = acc;
    for (int s = 32; s > 0; s >>= 1) m = fmaxf(m, __shfl_xor(m, s, 64));
    float ex = __expf(acc - m);
    float sum = ex;
    for (int s = 32; s > 0; s >>= 1) sum += __shfl_xor(sum, s, 64);
    out[(size_t)gr * NCLS + c] = acc - m - __logf(sum);
}

// ---------------- launch ----------------

extern "C" void kernel_launch(void* const* d_in, const int* in_sizes, int n_in,
                              void* d_out, int out_size, void* d_ws, size_t ws_size,
                              hipStream_t stream) {
    const float* x = (const float*)d_in[0];
    const int* ei = (const int*)d_in[1];
    const int* batch = (const int*)d_in[2];
    const float* W1 = (const float*)d_in[3];
    const float* b1 = (const float*)d_in[4];
    const float* W2 = (const float*)d_in[5];
    const float* b2 = (const float*)d_in[6];
    const float* Wc = (const float*)d_in[7];
    const float* bc = (const float*)d_in[8];
    float* out = (float*)d_out;
    const int* src = ei;
    const int* dst = ei + N_EDGES;

    char* w = (char*)d_ws;
    auto take = [&](size_t n) { char* p = w; w += (n + 255) & ~(size_t)255; return p; };
    // contiguous zero-init region: gcnt | bsum | gpool
    int* gcnt = (int*)take((size_t)N_GRAPHS * 4);
    int* bsum = (int*)take((size_t)1024 * 4);
    float* gpool = (float*)take((size_t)N_GRAPHS * F1 * 4);
    size_t zspan = (size_t)N_GRAPHS * 4 + 1024 * 4 + (size_t)N_GRAPHS * F1 * 4;

    float* dinv = (float*)take((size_t)N_NODES * 4);
    int* offs = (int*)take((size_t)(N_NODES + 1) * 4);
    int* hist = (int*)take((size_t)FLATN * 4);
    int* histoff = (int*)take((size_t)(FLATN + 1) * 4);
    uint32* pairs = (uint32*)take((size_t)N_EDGES * 4);
    int* csr = (int*)take((size_t)N_EDGES * 4);
    u16* q8x = (u16*)take((size_t)N_NODES * 64 * 2);        // biased u8 x*dinv rows (128 B/row)
    float* qsx = (float*)take((size_t)N_NODES * 4);
    uint32* q8h = (uint32*)take((size_t)N_NODES * 64 * 4);  // biased u8 h1*dinv rows (256 B/row)
    float* qsh = (float*)take((size_t)N_NODES * 4);
    u16* aggx = (u16*)take((size_t)(N_NODES + 64) * F0 * 2);  // bf16, +64 rows GEMM overread pad
    u16* agg1 = (u16*)take((size_t)(N_NODES + 64) * F1 * 2);  // bf16, +64 rows pad
    u16* W1t = (u16*)take((size_t)F0 * F1 * 2);
    u16* W2t = (u16*)take((size_t)F1 * F1 * 2);

    hipMemsetAsync(gcnt, 0, zspan, stream);

    // CSR build: hist(+bsum) -> scan_final -> bin -> per-bucket finalize
    hist_pass<<<NCHUNK, 256, 0, stream>>>(dst, hist, bsum);
    {
        int nb = (FLATN + SCAN_B - 1) / SCAN_B;  // 75
        scan_final<<<nb, SCAN_B, 0, stream>>>(hist, FLATN, bsum, nb, histoff);
    }
    bin_pairs<<<NCHUNK, 256, 0, stream>>>(src, dst, histoff, pairs);
    bucket_csr<<<NB, 256, 0, stream>>>(pairs, histoff, offs, csr, dinv);

    // weight prep + x quantize (scaled by dinv; also counts batch) — full-occupancy grids
    transpose_w2<<<(F0 * F1 + F1 * F1 + 255) / 256, 256, 0, stream>>>(W1, W2, W1t, W2t);
    cast_q8_x<<<(N_NODES + 3) / 4, 256, 0, stream>>>(x, dinv, batch, q8x, qsx, gcnt);

    int mblocks = (N_NODES + 63) / 64;  // 1563

    // conv1: u8 gather-aggregate -> bf16, MFMA GEMM (+b1, relu, *dinv) + fused quantize -> q8h
    aggregate_q8<F0><<<(N_NODES + 3) / 4, 256, 0, stream>>>(q8x, qsx, offs, csr, dinv, aggx);
    gemm_fused<F0, true><<<mblocks, 256, 0, stream>>>(aggx, W1t, b1, dinv, N_NODES,
                                                      q8h, qsh, nullptr, nullptr);

    // conv2: u8 gather-aggregate -> bf16, MFMA GEMM (+b2, relu) + fused mean-pool
    aggregate_q8<F1><<<(N_NODES + 3) / 4, 256, 0, stream>>>(q8h, qsh, offs, csr, dinv, agg1);
    gemm_fused<F1, false><<<mblocks, 256, 0, stream>>>(agg1, W2t, b2, dinv, N_NODES,
                                                       nullptr, nullptr, batch, gpool);

    // classifier + log_softmax
    classify<<<N_GRAPHS, 64, 0, stream>>>(gpool, gcnt, Wc, bc, out);
}

// Round 11
// 445.305 us; speedup vs baseline: 1.4486x; 1.2883x over previous
//
#include <hip/hip_runtime.h>
#include <hip/hip_bf16.h>

#define N_NODES 100000
#define N_EDGES 1600000
#define N_GRAPHS 2048
#define F0 128
#define F1 256
#define NCLS 64

// bucketed CSR build
#define BSHIFT 9
#define BNODES 512
#define NB 196
#define EPB 4096
#define NCHUNK 391
#define FLATN (NB * NCHUNK)

typedef unsigned int uint32;
typedef unsigned short u16;
typedef u16 u16x8 __attribute__((ext_vector_type(8)));
typedef __bf16 bf16x8 __attribute__((ext_vector_type(8)));
typedef float f32x4 __attribute__((ext_vector_type(4)));

__device__ __forceinline__ float b16f(u16 v) { return __builtin_bit_cast(float, (uint32)v << 16); }
__device__ __forceinline__ u16 f2bf(float f) {
    uint32 u = __builtin_bit_cast(uint32, f);
    u += 0x7fffu + ((u >> 16) & 1u);  // RNE
    return (u16)(u >> 16);
}
__device__ __forceinline__ uint32 pack2(float a, float b) {
    return (uint32)f2bf(a) | ((uint32)f2bf(b) << 16);
}
// biased-u8 dequant helpers: compiler emits v_cvt_f32_ubyte0..3
__device__ __forceinline__ float ub0(uint32 u) { return (float)(u & 255u); }
__device__ __forceinline__ float ub1(uint32 u) { return (float)((u >> 8) & 255u); }
__device__ __forceinline__ float ub2(uint32 u) { return (float)((u >> 16) & 255u); }
__device__ __forceinline__ float ub3(uint32 u) { return (float)(u >> 24); }

// async global->LDS, 16 B per lane, deposit at wave-uniform base + lane*16
#define GLOAD_LDS16(g, l)                                                                  \
    __builtin_amdgcn_global_load_lds((const __attribute__((address_space(1))) void*)(g),   \
                                     (__attribute__((address_space(3))) void*)(l), 16, 0, 0)

// ---------------- scans ----------------
#define SCAN_B 1024

// per-1024-chunk sums via LDS tree (NO global atomics — R10 lesson: 76k far atomics
// onto 5 cache lines cost 147 us; this kernel costs ~5 us)
__global__ void scan_partial(const int* __restrict__ in, int n, int* __restrict__ bsum) {
    __shared__ int lds[SCAN_B];
    int i = blockIdx.x * SCAN_B + threadIdx.x;
    lds[threadIdx.x] = (i < n) ? in[i] : 0;
    __syncthreads();
    for (int s = SCAN_B / 2; s > 0; s >>= 1) {
        if (threadIdx.x < s) lds[threadIdx.x] += lds[threadIdx.x + s];
        __syncthreads();
    }
    if (threadIdx.x == 0) bsum[blockIdx.x] = lds[0];
}

// scan_final with inlined block-prefix of partials (nb <= 128)
__global__ void scan_final(const int* __restrict__ in, int n, const int* __restrict__ bsum,
                           int nb, int* __restrict__ out) {
    __shared__ int lds[SCAN_B];
    __shared__ int bpre[128];
    if (threadIdx.x < 128) bpre[threadIdx.x] = (threadIdx.x < nb) ? bsum[threadIdx.x] : 0;
    __syncthreads();
    for (int s = 1; s < 128; s <<= 1) {
        int v = (threadIdx.x < 128 && threadIdx.x >= s) ? bpre[threadIdx.x - s] : 0;
        __syncthreads();
        if (threadIdx.x < 128) bpre[threadIdx.x] += v;
        __syncthreads();
    }
    int base = (blockIdx.x > 0) ? bpre[blockIdx.x - 1] : 0;
    int i = blockIdx.x * SCAN_B + threadIdx.x;
    int v = (i < n) ? in[i] : 0;
    lds[threadIdx.x] = v;
    __syncthreads();
    for (int s = 1; s < SCAN_B; s <<= 1) {
        int t = (threadIdx.x >= s) ? lds[threadIdx.x - s] : 0;
        __syncthreads();
        lds[threadIdx.x] += t;
        __syncthreads();
    }
    if (i < n) out[i + 1] = lds[threadIdx.x] + base;
    if (i == 0) out[0] = 0;
}

// ---------------- bucketed CSR build ----------------

// plain hist: LDS atomics only, coalesced global writes
__global__ __launch_bounds__(256) void hist_pass(const int* __restrict__ dst,
                                                 int* __restrict__ hist) {
    __shared__ int lh[NB];
    int t = threadIdx.x, blk = blockIdx.x;
    if (t < NB) lh[t] = 0;
    __syncthreads();
#pragma unroll
    for (int k = 0; k < EPB / 256; ++k) {
        int e = blk * EPB + k * 256 + t;
        if (e < N_EDGES) atomicAdd(&lh[dst[e] >> BSHIFT], 1);
    }
    __syncthreads();
    if (t < NB) hist[t * NCHUNK + blk] = lh[t];
}

__global__ __launch_bounds__(256) void bin_pairs(const int* __restrict__ src,
                                                 const int* __restrict__ dst,
                                                 const int* __restrict__ histoff,
                                                 uint32* __restrict__ pairs) {
    __shared__ int lbase[NB];
    __shared__ int lcur[NB];
    int t = threadIdx.x, blk = blockIdx.x;
    if (t < NB) {
        lbase[t] = histoff[t * NCHUNK + blk];
        lcur[t] = 0;
    }
    __syncthreads();
#pragma unroll
    for (int k = 0; k < EPB / 256; ++k) {
        int e = blk * EPB + k * 256 + t;
        if (e < N_EDGES) {
            int d = dst[e], s = src[e];
            int b = d >> BSHIFT;
            int r = atomicAdd(&lcur[b], 1);
            pairs[lbase[b] + r] = (uint32)(d & (BNODES - 1)) | ((uint32)s << BSHIFT);
        }
    }
}

#define PCAP 16384

// per-bucket CSR finalize: deg->dinv, offs, csr
__global__ __launch_bounds__(256) void bucket_csr(const uint32* __restrict__ pairs,
                                                  const int* __restrict__ histoff,
                                                  int* __restrict__ offs,
                                                  int* __restrict__ csr,
                                                  float* __restrict__ dinv) {
    __shared__ uint32 lp[PCAP];
    __shared__ int lcnt[BNODES];
    __shared__ int lcur[BNODES];
    __shared__ int psum[256];
    int t = threadIdx.x, b = blockIdx.x;
    int n0 = b << BSHIFT;
    int nn = min(BNODES, N_NODES - n0);
    lcnt[t] = 0;
    lcnt[t + 256] = 0;
    __syncthreads();
    int ebase = histoff[b * NCHUNK];
    int eend = (b == NB - 1) ? N_EDGES : histoff[(b + 1) * NCHUNK];
    for (int i = ebase + t; i < eend; i += 256) {
        uint32 p = pairs[i];
        int li = i - ebase;
        if (li < PCAP) lp[li] = p;
        atomicAdd(&lcnt[p & (BNODES - 1)], 1);
    }
    __syncthreads();
    int c0 = lcnt[2 * t], c1 = lcnt[2 * t + 1];
    if (2 * t < nn) dinv[n0 + 2 * t] = rsqrtf((float)(c0 + 1));
    if (2 * t + 1 < nn) dinv[n0 + 2 * t + 1] = rsqrtf((float)(c1 + 1));
    psum[t] = c0 + c1;
    __syncthreads();
    for (int s = 1; s < 256; s <<= 1) {
        int v = (t >= s) ? psum[t - s] : 0;
        __syncthreads();
        psum[t] += v;
        __syncthreads();
    }
    int ep = psum[t] - (c0 + c1);
    lcur[2 * t] = ep;
    lcur[2 * t + 1] = ep + c0;
    if (2 * t < nn) offs[n0 + 2 * t] = ebase + ep;
    if (2 * t + 1 < nn) offs[n0 + 2 * t + 1] = ebase + ep + c0;
    if (b == NB - 1 && t == 0) offs[N_NODES] = N_EDGES;
    __syncthreads();
    for (int i = ebase + t; i < eend; i += 256) {
        int li = i - ebase;
        uint32 p = (li < PCAP) ? lp[li] : pairs[i];
        int r = atomicAdd(&lcur[p & (BNODES - 1)], 1);
        csr[ebase + r] = (int)(p >> BSHIFT);
    }
}

// ---------------- quantize x: biased u8 row + fp32 scale; fuses count_batch ----------------
// standalone at 25k blocks: this work needs full-device occupancy (R9 lesson)

__global__ __launch_bounds__(256) void cast_q8_x(const float* __restrict__ x,
                                                 const float* __restrict__ dinv,
                                                 const int* __restrict__ batch,
                                                 u16* __restrict__ q8,
                                                 float* __restrict__ qs,
                                                 int* __restrict__ gcnt) {
    int node = blockIdx.x * 4 + (threadIdx.x >> 6);
    if (node >= N_NODES) return;
    int lane = threadIdx.x & 63;
    float d = dinv[node];
    float2 v = *(const float2*)&x[(size_t)node * F0 + lane * 2];
    float f0 = v.x * d, f1 = v.y * d;
    float m = fmaxf(fabsf(f0), fabsf(f1));
    for (int s = 32; s > 0; s >>= 1) m = fmaxf(m, __shfl_xor(m, s, 64));
    float inv = (m > 0.f) ? 127.f / m : 0.f;
    int u0 = (int)rintf(f0 * inv) + 128, u1 = (int)rintf(f1 * inv) + 128;
    q8[(size_t)node * 64 + lane] = (u16)((u0 & 255) | ((u1 & 255) << 8));
    if (lane == 0) {
        qs[node] = m * (1.f / 127.f);
        atomicAdd(&gcnt[batch[node]], 1);
    }
}

// ---------------- weight transpose+cast ----------------

__global__ void transpose_w2(const float* __restrict__ W1, const float* __restrict__ W2,
                             u16* __restrict__ W1t, u16* __restrict__ W2t) {
    int id = blockIdx.x * blockDim.x + threadIdx.x;
    if (id < F0 * F1) {
        int k = id / F1, n = id % F1;
        W1t[(size_t)n * F0 + k] = f2bf(W1[id]);
    } else {
        int id2 = id - F0 * F1;
        if (id2 < F1 * F1) {
            int k = id2 / F1, n = id2 % F1;
            W2t[(size_t)n * F1 + k] = f2bf(W2[id2]);
        }
    }
}

// ---------------- biased-u8 gather aggregation (standalone, high occupancy) ----------------
// deq(j) = (u8 - 128)*qs[j] = h[j]*dinv[j];
// out[i] = bf16( dinv[i] * (sum_j deq(j) + deq(i)) ), via acc - 128*sum(scales)

template <int F>
__global__ __launch_bounds__(256) void aggregate_q8(const void* __restrict__ q8,
                                                    const float* __restrict__ qs,
                                                    const int* __restrict__ offs,
                                                    const int* __restrict__ csr,
                                                    const float* __restrict__ dinv,
                                                    u16* __restrict__ out) {
    constexpr int V = F / 64;
    int node = blockIdx.x * 4 + (threadIdx.x >> 6);
    if (node >= N_NODES) return;
    int lane = threadIdx.x & 63;
    float acc[V];
    float ssum;
    {
        float s = qs[node];
        ssum = s;
        if constexpr (V == 2) {
            uint32 q = (uint32)((const u16*)q8)[(size_t)node * 64 + lane];
            acc[0] = ub0(q) * s;
            acc[1] = ub1(q) * s;
        } else {
            uint32 q = ((const uint32*)q8)[(size_t)node * 64 + lane];
            acc[0] = ub0(q) * s;
            acc[1] = ub1(q) * s;
            acc[2] = ub2(q) * s;
            acc[3] = ub3(q) * s;
        }
    }
    int e0 = offs[node], e1 = offs[node + 1];
    for (int b = e0; b < e1; b += 64) {
        bool valid = (b + lane) < e1;
        int idx = valid ? csr[b + lane] : 0;
        float sv = valid ? qs[idx] : 0.f;
        int cnt = min(64, e1 - b);
        int t = 0;
        // 8-deep row pipeline
        for (; t + 8 <= cnt; t += 8) {
            int j[8];
            float s[8];
#pragma unroll
            for (int u = 0; u < 8; ++u) {
                j[u] = __shfl(idx, t + u);
                s[u] = __shfl(sv, t + u);
            }
            uint32 a[8];
#pragma unroll
            for (int u = 0; u < 8; ++u) {
                if constexpr (V == 2)
                    a[u] = (uint32)((const u16*)q8)[(size_t)j[u] * 64 + lane];
                else
                    a[u] = ((const uint32*)q8)[(size_t)j[u] * 64 + lane];
            }
#pragma unroll
            for (int u = 0; u < 8; ++u) {
                ssum += s[u];
                acc[0] += ub0(a[u]) * s[u];
                acc[1] += ub1(a[u]) * s[u];
                if constexpr (V == 4) {
                    acc[2] += ub2(a[u]) * s[u];
                    acc[3] += ub3(a[u]) * s[u];
                }
            }
        }
        for (; t < cnt; ++t) {
            int j0 = __shfl(idx, t);
            float s0 = __shfl(sv, t);
            ssum += s0;
            uint32 a;
            if constexpr (V == 2)
                a = (uint32)((const u16*)q8)[(size_t)j0 * 64 + lane];
            else
                a = ((const uint32*)q8)[(size_t)j0 * 64 + lane];
            acc[0] += ub0(a) * s0;
            acc[1] += ub1(a) * s0;
            if constexpr (V == 4) {
                acc[2] += ub2(a) * s0;
                acc[3] += ub3(a) * s0;
            }
        }
    }
    float di = dinv[node];
    float bb = 128.f * ssum;
    u16* orow = out + (size_t)node * F + lane * V;
    if constexpr (V == 2) {
        *(uint32*)orow = pack2((acc[0] - bb) * di, (acc[1] - bb) * di);
    } else {
        uint2 o;
        o.x = pack2((acc[0] - bb) * di, (acc[1] - bb) * di);
        o.y = pack2((acc[2] - bb) * di, (acc[3] - bb) * di);
        *(uint2*)orow = o;
    }
}

// ---------------- bf16 MFMA GEMM, BM=64 x BN=256, global_load_lds staging ----------------
// A rows read unguarded (caller pads A by >=64 rows).
// QUANT=true : epilogue = bias+relu, *dinv, row-absmax -> biased-u8 q8 + fp32 qs
// QUANT=false: epilogue = bias+relu -> fused mean-pool atomics into gpool

template <int K, bool QUANT>
__global__ __launch_bounds__(256) void gemm_fused(const u16* __restrict__ A,
                                                  const u16* __restrict__ Bt,
                                                  const float* __restrict__ bias,
                                                  const float* __restrict__ dinv,
                                                  int M,
                                                  uint32* __restrict__ q8,
                                                  float* __restrict__ qs,
                                                  const int* __restrict__ batch,
                                                  float* __restrict__ gpool) {
    constexpr int BM = 64, BN = 256, BK = 64;
    __shared__ __align__(16) char smem[40960];
    u16* As = (u16*)smem;
    u16* Bs = (u16*)smem + BM * BK;
    int tid = threadIdx.x;
    int lane = tid & 63;
    int wid = __builtin_amdgcn_readfirstlane(tid >> 6);
    int row0 = blockIdx.x * BM;
    int lr = lane & 15, lq = lane >> 4;
    int wn = wid * 64;
    int srow = lane >> 3;
    int schunk = (lane & 7) * 8;

    f32x4 acc[4][4];
#pragma unroll
    for (int i = 0; i < 4; ++i)
#pragma unroll
        for (int j = 0; j < 4; ++j) acc[i][j] = (f32x4){0.f, 0.f, 0.f, 0.f};

    for (int k0 = 0; k0 < K; k0 += BK) {
#pragma unroll
        for (int p = 0; p < 2; ++p) {
            int r0 = wid * 16 + p * 8;
            const u16* g = A + (size_t)(row0 + r0 + srow) * K + k0 + schunk;
            GLOAD_LDS16(g, As + r0 * BK);
        }
#pragma unroll
        for (int p = 0; p < 8; ++p) {
            int r0 = wid * 64 + p * 8;
            const u16* g = Bt + (size_t)(r0 + srow) * K + k0 + schunk;
            GLOAD_LDS16(g, Bs + r0 * BK);
        }
        __syncthreads();
#pragma unroll
        for (int kk = 0; kk < BK; kk += 32) {
            bf16x8 af[4], bfr[4];
#pragma unroll
            for (int i = 0; i < 4; ++i)
                af[i] = __builtin_bit_cast(bf16x8, *(const u16x8*)&As[(i * 16 + lr) * BK + kk + lq * 8]);
#pragma unroll
            for (int j = 0; j < 4; ++j)
                bfr[j] = __builtin_bit_cast(bf16x8, *(const u16x8*)&Bs[(wn + j * 16 + lr) * BK + kk + lq * 8]);
#pragma unroll
            for (int i = 0; i < 4; ++i)
#pragma unroll
                for (int j = 0; j < 4; ++j)
                    acc[i][j] = __builtin_amdgcn_mfma_f32_16x16x32_bf16(af[i], bfr[j], acc[i][j], 0, 0, 0);
        }
        __syncthreads();
    }

    // epilogue tile P[64][260] bf16 (overlays As/Bs)
    u16(*P)[260] = (u16(*)[260])smem;
#pragma unroll
    for (int i = 0; i < 4; ++i) {
#pragma unroll
        for (int j = 0; j < 4; ++j) {
            int cl = wn + j * 16 + lr;
            float bv = bias[cl];
#pragma unroll
            for (int r = 0; r < 4; ++r) {
                int rl = i * 16 + lq * 4 + r;
                int row = row0 + rl;
                float v = 0.f;
                if (row < M) {
                    v = fmaxf(acc[i][j][r] + bv, 0.f);
                    if constexpr (QUANT) v *= dinv[row];
                }
                P[rl][cl] = f2bf(v);
            }
        }
    }

    if constexpr (QUANT) {
        float* rmax = (float*)(smem + 33280);  // [4][64]
        __syncthreads();
        int row = tid & 63, q = tid >> 6;
        float m = 0.f;
#pragma unroll 8
        for (int i = 0; i < 64; ++i) m = fmaxf(m, b16f(P[row][q * 64 + i]));  // post-relu >= 0
        rmax[q * 64 + row] = m;
        __syncthreads();
        m = fmaxf(fmaxf(rmax[row], rmax[64 + row]), fmaxf(rmax[128 + row], rmax[192 + row]));
        int gr = row0 + row;
        if (gr < M) {
            float inv = (m > 0.f) ? 127.f / m : 0.f;
#pragma unroll
            for (int d = 0; d < 16; d += 4) {
                uint32 dw[4];
#pragma unroll
                for (int e = 0; e < 4; ++e) {
                    int cb = q * 64 + (d + e) * 4;
                    uint32 v0 = (uint32)((int)rintf(b16f(P[row][cb + 0]) * inv) + 128);
                    uint32 v1 = (uint32)((int)rintf(b16f(P[row][cb + 1]) * inv) + 128);
                    uint32 v2 = (uint32)((int)rintf(b16f(P[row][cb + 2]) * inv) + 128);
                    uint32 v3 = (uint32)((int)rintf(b16f(P[row][cb + 3]) * inv) + 128);
                    dw[e] = v0 | (v1 << 8) | (v2 << 16) | (v3 << 24);
                }
                *(uint4*)&q8[(size_t)gr * 64 + q * 16 + d] = make_uint4(dw[0], dw[1], dw[2], dw[3]);
            }
            if (q == 0) qs[gr] = m * (1.f / 127.f);
        }
    } else {
        int* batchl = (int*)(smem + 33280);  // [64]
        if (tid < BM) {
            int row = row0 + tid;
            batchl[tid] = batch[row < M ? row : (M - 1)];
        }
        __syncthreads();
        int c = tid;  // one column per thread
        int nrows = min(BM, M - row0);
        int cur = batchl[0];
        float sum = 0.f;
        for (int r = 0; r < nrows; ++r) {
            int gb = batchl[r];
            float v = b16f(P[r][c]);
            if (gb != cur) {
                atomicAdd(&gpool[(size_t)cur * BN + c], sum);
                sum = 0.f;
                cur = gb;
            }
            sum += v;
        }
        atomicAdd(&gpool[(size_t)cur * BN + c], sum);
    }
}

// ---------------- classifier + log_softmax ----------------

__global__ void classify(const float* __restrict__ gpool, const int* __restrict__ gcnt,
                         const float* __restrict__ Wc, const float* __restrict__ bc,
                         float* __restrict__ out) {
    int gr = blockIdx.x;
    int c = threadIdx.x;  // 0..63, single wave
    __shared__ float gl[F1];
    float inv = 1.f / fmaxf((float)gcnt[gr], 1.f);
    for (int k = c; k < F1; k += 64) gl[k] = gpool[(size_t)gr * F1 + k] * inv;
    __syncthreads();
    float acc = bc[c];
    for (int k = 0; k < F1; ++k) acc += gl[k] * Wc[k * NCLS + c];
    float m = acc;
    for (int s = 32; s > 0; s >>= 1) m = fmaxf(m, __shfl_xor(m, s, 64));
    float ex = __expf(acc - m);
    float sum = ex;
    for (int s = 32; s > 0; s >>= 1) sum += __shfl_xor(sum, s, 64);
    out[(size_t)gr * NCLS + c] = acc - m - __logf(sum);
}

// ---------------- launch ----------------

extern "C" void kernel_launch(void* const* d_in, const int* in_sizes, int n_in,
                              void* d_out, int out_size, void* d_ws, size_t ws_size,
                              hipStream_t stream) {
    const float* x = (const float*)d_in[0];
    const int* ei = (const int*)d_in[1];
    const int* batch = (const int*)d_in[2];
    const float* W1 = (const float*)d_in[3];
    const float* b1 = (const float*)d_in[4];
    const float* W2 = (const float*)d_in[5];
    const float* b2 = (const float*)d_in[6];
    const float* Wc = (const float*)d_in[7];
    const float* bc = (const float*)d_in[8];
    float* out = (float*)d_out;
    const int* src = ei;
    const int* dst = ei + N_EDGES;

    char* w = (char*)d_ws;
    auto take = [&](size_t n) { char* p = w; w += (n + 255) & ~(size_t)255; return p; };
    // contiguous zero-init region: gcnt | gpool
    int* gcnt = (int*)take((size_t)N_GRAPHS * 4);
    float* gpool = (float*)take((size_t)N_GRAPHS * F1 * 4);
    size_t zspan = (size_t)N_GRAPHS * 4 + (size_t)N_GRAPHS * F1 * 4;

    int* bsum = (int*)take((size_t)1024 * 4);
    float* dinv = (float*)take((size_t)N_NODES * 4);
    int* offs = (int*)take((size_t)(N_NODES + 1) * 4);
    int* hist = (int*)take((size_t)FLATN * 4);
    int* histoff = (int*)take((size_t)(FLATN + 1) * 4);
    uint32* pairs = (uint32*)take((size_t)N_EDGES * 4);
    int* csr = (int*)take((size_t)N_EDGES * 4);
    u16* q8x = (u16*)take((size_t)N_NODES * 64 * 2);        // biased u8 x*dinv rows (128 B/row)
    float* qsx = (float*)take((size_t)N_NODES * 4);
    uint32* q8h = (uint32*)take((size_t)N_NODES * 64 * 4);  // biased u8 h1*dinv rows (256 B/row)
    float* qsh = (float*)take((size_t)N_NODES * 4);
    u16* aggx = (u16*)take((size_t)(N_NODES + 64) * F0 * 2);  // bf16, +64 rows GEMM overread pad
    u16* agg1 = (u16*)take((size_t)(N_NODES + 64) * F1 * 2);  // bf16, +64 rows pad
    u16* W1t = (u16*)take((size_t)F0 * F1 * 2);
    u16* W2t = (u16*)take((size_t)F1 * F1 * 2);

    hipMemsetAsync(gcnt, 0, zspan, stream);

    // CSR build: hist -> scan_partial -> scan_final -> bin -> per-bucket finalize
    hist_pass<<<NCHUNK, 256, 0, stream>>>(dst, hist);
    {
        int nb = (FLATN + SCAN_B - 1) / SCAN_B;  // 75
        scan_partial<<<nb, SCAN_B, 0, stream>>>(hist, FLATN, bsum);
        scan_final<<<nb, SCAN_B, 0, stream>>>(hist, FLATN, bsum, nb, histoff);
    }
    bin_pairs<<<NCHUNK, 256, 0, stream>>>(src, dst, histoff, pairs);
    bucket_csr<<<NB, 256, 0, stream>>>(pairs, histoff, offs, csr, dinv);

    // weight prep + x quantize (scaled by dinv; also counts batch) — full-occupancy grids
    transpose_w2<<<(F0 * F1 + F1 * F1 + 255) / 256, 256, 0, stream>>>(W1, W2, W1t, W2t);
    cast_q8_x<<<(N_NODES + 3) / 4, 256, 0, stream>>>(x, dinv, batch, q8x, qsx, gcnt);

    int mblocks = (N_NODES + 63) / 64;  // 1563

    // conv1: u8 gather-aggregate -> bf16, MFMA GEMM (+b1, relu, *dinv) + fused quantize -> q8h
    aggregate_q8<F0><<<(N_NODES + 3) / 4, 256, 0, stream>>>(q8x, qsx, offs, csr, dinv, aggx);
    gemm_fused<F0, true><<<mblocks, 256, 0, stream>>>(aggx, W1t, b1, dinv, N_NODES,
                                                      q8h, qsh, nullptr, nullptr);

    // conv2: u8 gather-aggregate -> bf16, MFMA GEMM (+b2, relu) + fused mean-pool
    aggregate_q8<F1><<<(N_NODES + 3) / 4, 256, 0, stream>>>(q8h, qsh, offs, csr, dinv, agg1);
    gemm_fused<F1, false><<<mblocks, 256, 0, stream>>>(agg1, W2t, b2, dinv, N_NODES,
                                                       nullptr, nullptr, batch, gpool);

    // classifier + log_softmax
    classify<<<N_GRAPHS, 64, 0, stream>>>(gpool, gcnt, Wc, bc, out);
}

// Round 12
// 428.080 us; speedup vs baseline: 1.5068x; 1.0402x over previous
//
#include <hip/hip_runtime.h>
#include <hip/hip_bf16.h>

#define N_NODES 100000
#define N_EDGES 1600000
#define N_GRAPHS 2048
#define F0 128
#define F1 256
#define NCLS 64

// bucketed CSR build
#define BSHIFT 9
#define BNODES 512
#define NB 196
#define EPB 4096
#define NCHUNK 391
#define FLATN (NB * NCHUNK)

typedef unsigned int uint32;
typedef unsigned short u16;
typedef u16 u16x8 __attribute__((ext_vector_type(8)));
typedef __bf16 bf16x8 __attribute__((ext_vector_type(8)));
typedef float f32x4 __attribute__((ext_vector_type(4)));

__device__ __forceinline__ float b16f(u16 v) { return __builtin_bit_cast(float, (uint32)v << 16); }
__device__ __forceinline__ u16 f2bf(float f) {
    uint32 u = __builtin_bit_cast(uint32, f);
    u += 0x7fffu + ((u >> 16) & 1u);  // RNE
    return (u16)(u >> 16);
}
__device__ __forceinline__ uint32 pack2(float a, float b) {
    return (uint32)f2bf(a) | ((uint32)f2bf(b) << 16);
}
// biased-u8 dequant helpers: compiler emits v_cvt_f32_ubyte0..3
__device__ __forceinline__ float ub0(uint32 u) { return (float)(u & 255u); }
__device__ __forceinline__ float ub1(uint32 u) { return (float)((u >> 8) & 255u); }
__device__ __forceinline__ float ub2(uint32 u) { return (float)((u >> 16) & 255u); }
__device__ __forceinline__ float ub3(uint32 u) { return (float)(u >> 24); }

// async global->LDS, 16 B per lane, deposit at wave-uniform base + lane*16
#define GLOAD_LDS16(g, l)                                                                  \
    __builtin_amdgcn_global_load_lds((const __attribute__((address_space(1))) void*)(g),   \
                                     (__attribute__((address_space(3))) void*)(l), 16, 0, 0)

// ---------------- scans ----------------
#define SCAN_B 1024

// per-1024-chunk sums via LDS tree (NO global atomics — R10 lesson: 76k far atomics
// onto 5 cache lines cost 147 us; this kernel costs ~5 us)
__global__ void scan_partial(const int* __restrict__ in, int n, int* __restrict__ bsum) {
    __shared__ int lds[SCAN_B];
    int i = blockIdx.x * SCAN_B + threadIdx.x;
    lds[threadIdx.x] = (i < n) ? in[i] : 0;
    __syncthreads();
    for (int s = SCAN_B / 2; s > 0; s >>= 1) {
        if (threadIdx.x < s) lds[threadIdx.x] += lds[threadIdx.x + s];
        __syncthreads();
    }
    if (threadIdx.x == 0) bsum[blockIdx.x] = lds[0];
}

// scan_final with inlined block-prefix of partials (nb <= 128)
__global__ void scan_final(const int* __restrict__ in, int n, const int* __restrict__ bsum,
                           int nb, int* __restrict__ out) {
    __shared__ int lds[SCAN_B];
    __shared__ int bpre[128];
    if (threadIdx.x < 128) bpre[threadIdx.x] = (threadIdx.x < nb) ? bsum[threadIdx.x] : 0;
    __syncthreads();
    for (int s = 1; s < 128; s <<= 1) {
        int v = (threadIdx.x < 128 && threadIdx.x >= s) ? bpre[threadIdx.x - s] : 0;
        __syncthreads();
        if (threadIdx.x < 128) bpre[threadIdx.x] += v;
        __syncthreads();
    }
    int base = (blockIdx.x > 0) ? bpre[blockIdx.x - 1] : 0;
    int i = blockIdx.x * SCAN_B + threadIdx.x;
    int v = (i < n) ? in[i] : 0;
    lds[threadIdx.x] = v;
    __syncthreads();
    for (int s = 1; s < SCAN_B; s <<= 1) {
        int t = (threadIdx.x >= s) ? lds[threadIdx.x - s] : 0;
        __syncthreads();
        lds[threadIdx.x] += t;
        __syncthreads();
    }
    if (i < n) out[i + 1] = lds[threadIdx.x] + base;
    if (i == 0) out[0] = 0;
}

// ---------------- bucketed CSR build ----------------

// plain hist: LDS atomics only, coalesced global writes
__global__ __launch_bounds__(256) void hist_pass(const int* __restrict__ dst,
                                                 int* __restrict__ hist) {
    __shared__ int lh[NB];
    int t = threadIdx.x, blk = blockIdx.x;
    if (t < NB) lh[t] = 0;
    __syncthreads();
#pragma unroll
    for (int k = 0; k < EPB / 256; ++k) {
        int e = blk * EPB + k * 256 + t;
        if (e < N_EDGES) atomicAdd(&lh[dst[e] >> BSHIFT], 1);
    }
    __syncthreads();
    if (t < NB) hist[t * NCHUNK + blk] = lh[t];
}

__global__ __launch_bounds__(256) void bin_pairs(const int* __restrict__ src,
                                                 const int* __restrict__ dst,
                                                 const int* __restrict__ histoff,
                                                 uint32* __restrict__ pairs) {
    __shared__ int lbase[NB];
    __shared__ int lcur[NB];
    int t = threadIdx.x, blk = blockIdx.x;
    if (t < NB) {
        lbase[t] = histoff[t * NCHUNK + blk];
        lcur[t] = 0;
    }
    __syncthreads();
#pragma unroll
    for (int k = 0; k < EPB / 256; ++k) {
        int e = blk * EPB + k * 256 + t;
        if (e < N_EDGES) {
            int d = dst[e], s = src[e];
            int b = d >> BSHIFT;
            int r = atomicAdd(&lcur[b], 1);
            pairs[lbase[b] + r] = (uint32)(d & (BNODES - 1)) | ((uint32)s << BSHIFT);
        }
    }
}

#define PCAP 16384

// per-bucket CSR finalize: deg->dinv, offs, csr
__global__ __launch_bounds__(256) void bucket_csr(const uint32* __restrict__ pairs,
                                                  const int* __restrict__ histoff,
                                                  int* __restrict__ offs,
                                                  int* __restrict__ csr,
                                                  float* __restrict__ dinv) {
    __shared__ uint32 lp[PCAP];
    __shared__ int lcnt[BNODES];
    __shared__ int lcur[BNODES];
    __shared__ int psum[256];
    int t = threadIdx.x, b = blockIdx.x;
    int n0 = b << BSHIFT;
    int nn = min(BNODES, N_NODES - n0);
    lcnt[t] = 0;
    lcnt[t + 256] = 0;
    __syncthreads();
    int ebase = histoff[b * NCHUNK];
    int eend = (b == NB - 1) ? N_EDGES : histoff[(b + 1) * NCHUNK];
    for (int i = ebase + t; i < eend; i += 256) {
        uint32 p = pairs[i];
        int li = i - ebase;
        if (li < PCAP) lp[li] = p;
        atomicAdd(&lcnt[p & (BNODES - 1)], 1);
    }
    __syncthreads();
    int c0 = lcnt[2 * t], c1 = lcnt[2 * t + 1];
    if (2 * t < nn) dinv[n0 + 2 * t] = rsqrtf((float)(c0 + 1));
    if (2 * t + 1 < nn) dinv[n0 + 2 * t + 1] = rsqrtf((float)(c1 + 1));
    psum[t] = c0 + c1;
    __syncthreads();
    for (int s = 1; s < 256; s <<= 1) {
        int v = (t >= s) ? psum[t - s] : 0;
        __syncthreads();
        psum[t] += v;
        __syncthreads();
    }
    int ep = psum[t] - (c0 + c1);
    lcur[2 * t] = ep;
    lcur[2 * t + 1] = ep + c0;
    if (2 * t < nn) offs[n0 + 2 * t] = ebase + ep;
    if (2 * t + 1 < nn) offs[n0 + 2 * t + 1] = ebase + ep + c0;
    if (b == NB - 1 && t == 0) offs[N_NODES] = N_EDGES;
    __syncthreads();
    for (int i = ebase + t; i < eend; i += 256) {
        int li = i - ebase;
        uint32 p = (li < PCAP) ? lp[li] : pairs[i];
        int r = atomicAdd(&lcur[p & (BNODES - 1)], 1);
        csr[ebase + r] = (int)(p >> BSHIFT);
    }
}

// ---------------- quantize x: biased u8 row + fp32 scale; fuses count_batch ----------------
// standalone at 25k blocks: needs full-device occupancy (R9 lesson)

__global__ __launch_bounds__(256) void cast_q8_x(const float* __restrict__ x,
                                                 const float* __restrict__ dinv,
                                                 const int* __restrict__ batch,
                                                 u16* __restrict__ q8,
                                                 float* __restrict__ qs,
                                                 int* __restrict__ gcnt) {
    int node = blockIdx.x * 4 + (threadIdx.x >> 6);
    if (node >= N_NODES) return;
    int lane = threadIdx.x & 63;
    float d = dinv[node];
    float2 v = *(const float2*)&x[(size_t)node * F0 + lane * 2];
    float f0 = v.x * d, f1 = v.y * d;
    float m = fmaxf(fabsf(f0), fabsf(f1));
    for (int s = 32; s > 0; s >>= 1) m = fmaxf(m, __shfl_xor(m, s, 64));
    float inv = (m > 0.f) ? 127.f / m : 0.f;
    int u0 = (int)rintf(f0 * inv) + 128, u1 = (int)rintf(f1 * inv) + 128;
    q8[(size_t)node * 64 + lane] = (u16)((u0 & 255) | ((u1 & 255) << 8));
    if (lane == 0) {
        qs[node] = m * (1.f / 127.f);
        atomicAdd(&gcnt[batch[node]], 1);
    }
}

// ---------------- weight transpose+cast ----------------

__global__ void transpose_w2(const float* __restrict__ W1, const float* __restrict__ W2,
                             u16* __restrict__ W1t, u16* __restrict__ W2t) {
    int id = blockIdx.x * blockDim.x + threadIdx.x;
    if (id < F0 * F1) {
        int k = id / F1, n = id % F1;
        W1t[(size_t)n * F0 + k] = f2bf(W1[id]);
    } else {
        int id2 = id - F0 * F1;
        if (id2 < F1 * F1) {
            int k = id2 / F1, n = id2 % F1;
            W2t[(size_t)n * F1 + k] = f2bf(W2[id2]);
        }
    }
}

// ---------------- biased-u8 gather aggregation (standalone, high occupancy) ----------------
// 4-deep pipeline, 24 VGPR (R11 lesson: 8-deep costs 36 VGPR -> occupancy 62% -> slower;
// TLP beats ILP for this mixed latency/BW kernel)
// deq(j) = (u8 - 128)*qs[j] = h[j]*dinv[j];
// out[i] = bf16( dinv[i] * (sum_j deq(j) + deq(i)) ), via acc - 128*sum(scales)

template <int F>
__global__ __launch_bounds__(256) void aggregate_q8(const void* __restrict__ q8,
                                                    const float* __restrict__ qs,
                                                    const int* __restrict__ offs,
                                                    const int* __restrict__ csr,
                                                    const float* __restrict__ dinv,
                                                    u16* __restrict__ out) {
    constexpr int V = F / 64;
    int node = blockIdx.x * 4 + (threadIdx.x >> 6);
    if (node >= N_NODES) return;
    int lane = threadIdx.x & 63;
    float acc[V];
    float ssum;
    {
        float s = qs[node];
        ssum = s;
        if constexpr (V == 2) {
            uint32 q = (uint32)((const u16*)q8)[(size_t)node * 64 + lane];
            acc[0] = ub0(q) * s;
            acc[1] = ub1(q) * s;
        } else {
            uint32 q = ((const uint32*)q8)[(size_t)node * 64 + lane];
            acc[0] = ub0(q) * s;
            acc[1] = ub1(q) * s;
            acc[2] = ub2(q) * s;
            acc[3] = ub3(q) * s;
        }
    }
    int e0 = offs[node], e1 = offs[node + 1];
    for (int b = e0; b < e1; b += 64) {
        bool valid = (b + lane) < e1;
        int idx = valid ? csr[b + lane] : 0;
        float sv = valid ? qs[idx] : 0.f;
        int cnt = min(64, e1 - b);
        int t = 0;
        for (; t + 4 <= cnt; t += 4) {
            int j0 = __shfl(idx, t), j1 = __shfl(idx, t + 1);
            int j2 = __shfl(idx, t + 2), j3 = __shfl(idx, t + 3);
            float s0 = __shfl(sv, t), s1 = __shfl(sv, t + 1);
            float s2 = __shfl(sv, t + 2), s3 = __shfl(sv, t + 3);
            ssum += (s0 + s1) + (s2 + s3);
            if constexpr (V == 2) {
                uint32 a = (uint32)((const u16*)q8)[(size_t)j0 * 64 + lane];
                uint32 c = (uint32)((const u16*)q8)[(size_t)j1 * 64 + lane];
                uint32 d = (uint32)((const u16*)q8)[(size_t)j2 * 64 + lane];
                uint32 f = (uint32)((const u16*)q8)[(size_t)j3 * 64 + lane];
                acc[0] += ub0(a) * s0 + ub0(c) * s1 + ub0(d) * s2 + ub0(f) * s3;
                acc[1] += ub1(a) * s0 + ub1(c) * s1 + ub1(d) * s2 + ub1(f) * s3;
            } else {
                uint32 a = ((const uint32*)q8)[(size_t)j0 * 64 + lane];
                uint32 c = ((const uint32*)q8)[(size_t)j1 * 64 + lane];
                uint32 d = ((const uint32*)q8)[(size_t)j2 * 64 + lane];
                uint32 f = ((const uint32*)q8)[(size_t)j3 * 64 + lane];
                acc[0] += ub0(a) * s0 + ub0(c) * s1 + ub0(d) * s2 + ub0(f) * s3;
                acc[1] += ub1(a) * s0 + ub1(c) * s1 + ub1(d) * s2 + ub1(f) * s3;
                acc[2] += ub2(a) * s0 + ub2(c) * s1 + ub2(d) * s2 + ub2(f) * s3;
                acc[3] += ub3(a) * s0 + ub3(c) * s1 + ub3(d) * s2 + ub3(f) * s3;
            }
        }
        for (; t < cnt; ++t) {
            int j0 = __shfl(idx, t);
            float s0 = __shfl(sv, t);
            ssum += s0;
            if constexpr (V == 2) {
                uint32 a = (uint32)((const u16*)q8)[(size_t)j0 * 64 + lane];
                acc[0] += ub0(a) * s0;
                acc[1] += ub1(a) * s0;
            } else {
                uint32 a = ((const uint32*)q8)[(size_t)j0 * 64 + lane];
                acc[0] += ub0(a) * s0;
                acc[1] += ub1(a) * s0;
                acc[2] += ub2(a) * s0;
                acc[3] += ub3(a) * s0;
            }
        }
    }
    float di = dinv[node];
    float bb = 128.f * ssum;
    u16* orow = out + (size_t)node * F + lane * V;
    if constexpr (V == 2) {
        *(uint32*)orow = pack2((acc[0] - bb) * di, (acc[1] - bb) * di);
    } else {
        uint2 o;
        o.x = pack2((acc[0] - bb) * di, (acc[1] - bb) * di);
        o.y = pack2((acc[2] - bb) * di, (acc[3] - bb) * di);
        *(uint2*)orow = o;
    }
}

// ---------------- bf16 MFMA GEMM, BM=64 x BN=256, global_load_lds staging ----------------
// A rows read unguarded (caller pads A by >=64 rows).
// QUANT=true : epilogue = bias+relu, *dinv, row-absmax -> biased-u8 q8 + fp32 qs
// QUANT=false: epilogue = bias+relu -> fused mean-pool atomics into gpool

template <int K, bool QUANT>
__global__ __launch_bounds__(256) void gemm_fused(const u16* __restrict__ A,
                                                  const u16* __restrict__ Bt,
                                                  const float* __restrict__ bias,
                                                  const float* __restrict__ dinv,
                                                  int M,
                                                  uint32* __restrict__ q8,
                                                  float* __restrict__ qs,
                                                  const int* __restrict__ batch,
                                                  float* __restrict__ gpool) {
    constexpr int BM = 64, BN = 256, BK = 64;
    __shared__ __align__(16) char smem[40960];
    u16* As = (u16*)smem;
    u16* Bs = (u16*)smem + BM * BK;
    int tid = threadIdx.x;
    int lane = tid & 63;
    int wid = __builtin_amdgcn_readfirstlane(tid >> 6);
    int row0 = blockIdx.x * BM;
    int lr = lane & 15, lq = lane >> 4;
    int wn = wid * 64;
    int srow = lane >> 3;
    int schunk = (lane & 7) * 8;

    f32x4 acc[4][4];
#pragma unroll
    for (int i = 0; i < 4; ++i)
#pragma unroll
        for (int j = 0; j < 4; ++j) acc[i][j] = (f32x4){0.f, 0.f, 0.f, 0.f};

    for (int k0 = 0; k0 < K; k0 += BK) {
#pragma unroll
        for (int p = 0; p < 2; ++p) {
            int r0 = wid * 16 + p * 8;
            const u16* g = A + (size_t)(row0 + r0 + srow) * K + k0 + schunk;
            GLOAD_LDS16(g, As + r0 * BK);
        }
#pragma unroll
        for (int p = 0; p < 8; ++p) {
            int r0 = wid * 64 + p * 8;
            const u16* g = Bt + (size_t)(r0 + srow) * K + k0 + schunk;
            GLOAD_LDS16(g, Bs + r0 * BK);
        }
        __syncthreads();
#pragma unroll
        for (int kk = 0; kk < BK; kk += 32) {
            bf16x8 af[4], bfr[4];
#pragma unroll
            for (int i = 0; i < 4; ++i)
                af[i] = __builtin_bit_cast(bf16x8, *(const u16x8*)&As[(i * 16 + lr) * BK + kk + lq * 8]);
#pragma unroll
            for (int j = 0; j < 4; ++j)
                bfr[j] = __builtin_bit_cast(bf16x8, *(const u16x8*)&Bs[(wn + j * 16 + lr) * BK + kk + lq * 8]);
#pragma unroll
            for (int i = 0; i < 4; ++i)
#pragma unroll
                for (int j = 0; j < 4; ++j)
                    acc[i][j] = __builtin_amdgcn_mfma_f32_16x16x32_bf16(af[i], bfr[j], acc[i][j], 0, 0, 0);
        }
        __syncthreads();
    }

    // epilogue tile P[64][260] bf16 (overlays As/Bs)
    u16(*P)[260] = (u16(*)[260])smem;
#pragma unroll
    for (int i = 0; i < 4; ++i) {
#pragma unroll
        for (int j = 0; j < 4; ++j) {
            int cl = wn + j * 16 + lr;
            float bv = bias[cl];
#pragma unroll
            for (int r = 0; r < 4; ++r) {
                int rl = i * 16 + lq * 4 + r;
                int row = row0 + rl;
                float v = 0.f;
                if (row < M) {
                    v = fmaxf(acc[i][j][r] + bv, 0.f);
                    if constexpr (QUANT) v *= dinv[row];
                }
                P[rl][cl] = f2bf(v);
            }
        }
    }

    if constexpr (QUANT) {
        float* rmax = (float*)(smem + 33280);  // [4][64]
        __syncthreads();
        int row = tid & 63, q = tid >> 6;
        float m = 0.f;
#pragma unroll 8
        for (int i = 0; i < 64; ++i) m = fmaxf(m, b16f(P[row][q * 64 + i]));  // post-relu >= 0
        rmax[q * 64 + row] = m;
        __syncthreads();
        m = fmaxf(fmaxf(rmax[row], rmax[64 + row]), fmaxf(rmax[128 + row], rmax[192 + row]));
        int gr = row0 + row;
        if (gr < M) {
            float inv = (m > 0.f) ? 127.f / m : 0.f;
#pragma unroll
            for (int d = 0; d < 16; d += 4) {
                uint32 dw[4];
#pragma unroll
                for (int e = 0; e < 4; ++e) {
                    int cb = q * 64 + (d + e) * 4;
                    uint32 v0 = (uint32)((int)rintf(b16f(P[row][cb + 0]) * inv) + 128);
                    uint32 v1 = (uint32)((int)rintf(b16f(P[row][cb + 1]) * inv) + 128);
                    uint32 v2 = (uint32)((int)rintf(b16f(P[row][cb + 2]) * inv) + 128);
                    uint32 v3 = (uint32)((int)rintf(b16f(P[row][cb + 3]) * inv) + 128);
                    dw[e] = v0 | (v1 << 8) | (v2 << 16) | (v3 << 24);
                }
                *(uint4*)&q8[(size_t)gr * 64 + q * 16 + d] = make_uint4(dw[0], dw[1], dw[2], dw[3]);
            }
            if (q == 0) qs[gr] = m * (1.f / 127.f);
        }
    } else {
        int* batchl = (int*)(smem + 33280);  // [64]
        if (tid < BM) {
            int row = row0 + tid;
            batchl[tid] = batch[row < M ? row : (M - 1)];
        }
        __syncthreads();
        int c = tid;  // one column per thread
        int nrows = min(BM, M - row0);
        int cur = batchl[0];
        float sum = 0.f;
        for (int r = 0; r < nrows; ++r) {
            int gb = batchl[r];
            float v = b16f(P[r][c]);
            if (gb != cur) {
                atomicAdd(&gpool[(size_t)cur * BN + c], sum);
                sum = 0.f;
                cur = gb;
            }
            sum += v;
        }
        atomicAdd(&gpool[(size_t)cur * BN + c], sum);
    }
}

// ---------------- classifier + log_softmax ----------------

__global__ void classify(const float* __restrict__ gpool, const int* __restrict__ gcnt,
                         const float* __restrict__ Wc, const float* __restrict__ bc,
                         float* __restrict__ out) {
    int gr = blockIdx.x;
    int c = threadIdx.x;  // 0..63, single wave
    __shared__ float gl[F1];
    float inv = 1.f / fmaxf((float)gcnt[gr], 1.f);
    for (int k = c; k < F1; k += 64) gl[k] = gpool[(size_t)gr * F1 + k] * inv;
    __syncthreads();
    float acc = bc[c];
    for (int k = 0; k < F1; ++k) acc += gl[k] * Wc[k * NCLS + c];
    float m = acc;
    for (int s = 32; s > 0; s >>= 1) m = fmaxf(m, __shfl_xor(m, s, 64));
    float ex = __expf(acc - m);
    float sum = ex;
    for (int s = 32; s > 0; s >>= 1) sum += __shfl_xor(sum, s, 64);
    out[(size_t)gr * NCLS + c] = acc - m - __logf(sum);
}

// ---------------- launch ----------------

extern "C" void kernel_launch(void* const* d_in, const int* in_sizes, int n_in,
                              void* d_out, int out_size, void* d_ws, size_t ws_size,
                              hipStream_t stream) {
    const float* x = (const float*)d_in[0];
    const int* ei = (const int*)d_in[1];
    const int* batch = (const int*)d_in[2];
    const float* W1 = (const float*)d_in[3];
    const float* b1 = (const float*)d_in[4];
    const float* W2 = (const float*)d_in[5];
    const float* b2 = (const float*)d_in[6];
    const float* Wc = (const float*)d_in[7];
    const float* bc = (const float*)d_in[8];
    float* out = (float*)d_out;
    const int* src = ei;
    const int* dst = ei + N_EDGES;

    char* w = (char*)d_ws;
    auto take = [&](size_t n) { char* p = w; w += (n + 255) & ~(size_t)255; return p; };
    // contiguous zero-init region: gcnt | gpool
    int* gcnt = (int*)take((size_t)N_GRAPHS * 4);
    float* gpool = (float*)take((size_t)N_GRAPHS * F1 * 4);
    size_t zspan = (size_t)N_GRAPHS * 4 + (size_t)N_GRAPHS * F1 * 4;

    int* bsum = (int*)take((size_t)1024 * 4);
    float* dinv = (float*)take((size_t)N_NODES * 4);
    int* offs = (int*)take((size_t)(N_NODES + 1) * 4);
    int* hist = (int*)take((size_t)FLATN * 4);
    int* histoff = (int*)take((size_t)(FLATN + 1) * 4);
    uint32* pairs = (uint32*)take((size_t)N_EDGES * 4);
    int* csr = (int*)take((size_t)N_EDGES * 4);
    u16* q8x = (u16*)take((size_t)N_NODES * 64 * 2);        // biased u8 x*dinv rows (128 B/row)
    float* qsx = (float*)take((size_t)N_NODES * 4);
    uint32* q8h = (uint32*)take((size_t)N_NODES * 64 * 4);  // biased u8 h1*dinv rows (256 B/row)
    float* qsh = (float*)take((size_t)N_NODES * 4);
    u16* aggx = (u16*)take((size_t)(N_NODES + 64) * F0 * 2);  // bf16, +64 rows GEMM overread pad
    u16* agg1 = (u16*)take((size_t)(N_NODES + 64) * F1 * 2);  // bf16, +64 rows pad
    u16* W1t = (u16*)take((size_t)F0 * F1 * 2);
    u16* W2t = (u16*)take((size_t)F1 * F1 * 2);

    hipMemsetAsync(gcnt, 0, zspan, stream);

    // CSR build: hist -> scan_partial -> scan_final -> bin -> per-bucket finalize
    hist_pass<<<NCHUNK, 256, 0, stream>>>(dst, hist);
    {
        int nb = (FLATN + SCAN_B - 1) / SCAN_B;  // 75
        scan_partial<<<nb, SCAN_B, 0, stream>>>(hist, FLATN, bsum);
        scan_final<<<nb, SCAN_B, 0, stream>>>(hist, FLATN, bsum, nb, histoff);
    }
    bin_pairs<<<NCHUNK, 256, 0, stream>>>(src, dst, histoff, pairs);
    bucket_csr<<<NB, 256, 0, stream>>>(pairs, histoff, offs, csr, dinv);

    // weight prep + x quantize (scaled by dinv; also counts batch) — full-occupancy grids
    transpose_w2<<<(F0 * F1 + F1 * F1 + 255) / 256, 256, 0, stream>>>(W1, W2, W1t, W2t);
    cast_q8_x<<<(N_NODES + 3) / 4, 256, 0, stream>>>(x, dinv, batch, q8x, qsx, gcnt);

    int mblocks = (N_NODES + 63) / 64;  // 1563

    // conv1: u8 gather-aggregate -> bf16, MFMA GEMM (+b1, relu, *dinv) + fused quantize -> q8h
    aggregate_q8<F0><<<(N_NODES + 3) / 4, 256, 0, stream>>>(q8x, qsx, offs, csr, dinv, aggx);
    gemm_fused<F0, true><<<mblocks, 256, 0, stream>>>(aggx, W1t, b1, dinv, N_NODES,
                                                      q8h, qsh, nullptr, nullptr);

    // conv2: u8 gather-aggregate -> bf16, MFMA GEMM (+b2, relu) + fused mean-pool
    aggregate_q8<F1><<<(N_NODES + 3) / 4, 256, 0, stream>>>(q8h, qsh, offs, csr, dinv, agg1);
    gemm_fused<F1, false><<<mblocks, 256, 0, stream>>>(agg1, W2t, b2, dinv, N_NODES,
                                                       nullptr, nullptr, batch, gpool);

    // classifier + log_softmax
    classify<<<N_GRAPHS, 64, 0, stream>>>(gpool, gcnt, Wc, bc, out);
}